// Round 1
// baseline (319.681 us; speedup 1.0000x reference)
//
#include <hip/hip_runtime.h>
#include <math.h>

#define BB 8
#define SS 64
#define NN 256
#define ST 128
#define IF 64
#define OF 64
#define H1 32
#define ALPHA 0.2f

// ---------------- Kernel 1: hyper MLPs -> W (512x4096), a (512x128) ----------
// 4 (b,s) pairs per block to amortize the 512KB w2 stream (read 128x not 512x).
__global__ __launch_bounds__(256) void k_hyper(
    const float* __restrict__ hyper,
    const float* __restrict__ w1, const float* __restrict__ b1,
    const float* __restrict__ w2, const float* __restrict__ b2,
    const float* __restrict__ aw1, const float* __restrict__ ab1,
    const float* __restrict__ aw2, const float* __restrict__ ab2,
    float* __restrict__ Wd, float* __restrict__ Aa)
{
    const int t = threadIdx.x;
    const int bs0 = blockIdx.x * 4;
    __shared__ float hy[4][ST];
    __shared__ float hdn[4][H1];
    __shared__ float hda[4][H1];
    for (int idx = t; idx < 4 * ST; idx += 256)
        hy[idx >> 7][idx & 127] = hyper[(size_t)bs0 * ST + idx];
    __syncthreads();
    if (t < 128) {
        const int q = t >> 5, c = t & 31;
        float acc = b1[c];
        for (int k = 0; k < ST; ++k) acc = fmaf(hy[q][k], w1[k * H1 + c], acc);
        hdn[q][c] = fmaxf(acc, 0.f);
    } else {
        const int tt = t - 128;
        const int q = tt >> 5, c = tt & 31;
        float acc = ab1[c];
        for (int k = 0; k < ST; ++k) acc = fmaf(hy[q][k], aw1[k * H1 + c], acc);
        hda[q][c] = fmaxf(acc, 0.f);
    }
    __syncthreads();
    // W = abs(hdn @ w2 + b2), 4096 outputs for each of the 4 bs
    for (int e = t; e < 4096; e += 256) {
        const float base = b2[e];
        float a0 = base, a1 = base, a2 = base, a3 = base;
        for (int k = 0; k < H1; ++k) {
            const float wv = w2[k * 4096 + e];
            a0 = fmaf(hdn[0][k], wv, a0);
            a1 = fmaf(hdn[1][k], wv, a1);
            a2 = fmaf(hdn[2][k], wv, a2);
            a3 = fmaf(hdn[3][k], wv, a3);
        }
        Wd[(size_t)(bs0 + 0) * 4096 + e] = fabsf(a0);
        Wd[(size_t)(bs0 + 1) * 4096 + e] = fabsf(a1);
        Wd[(size_t)(bs0 + 2) * 4096 + e] = fabsf(a2);
        Wd[(size_t)(bs0 + 3) * 4096 + e] = fabsf(a3);
    }
    if (t < 128) {
        const float base = ab2[t];
        float a0 = base, a1 = base, a2 = base, a3 = base;
        for (int k = 0; k < H1; ++k) {
            const float wv = aw2[k * 128 + t];
            a0 = fmaf(hda[0][k], wv, a0);
            a1 = fmaf(hda[1][k], wv, a1);
            a2 = fmaf(hda[2][k], wv, a2);
            a3 = fmaf(hda[3][k], wv, a3);
        }
        Aa[(size_t)(bs0 + 0) * 128 + t] = fabsf(a0);
        Aa[(size_t)(bs0 + 1) * 128 + t] = fabsf(a1);
        Aa[(size_t)(bs0 + 2) * 128 + t] = fabsf(a2);
        Aa[(size_t)(bs0 + 3) * 128 + t] = fabsf(a3);
    }
}

// ------------- Kernel: transpose Adj to float mask [j][i] (coalesce k_attn) --
__global__ void k_maskT(const int* __restrict__ Adj, float* __restrict__ maskT)
{
    const int i = blockIdx.x, j = threadIdx.x;
    maskT[j * NN + i] = (Adj[i * NN + j] > 0) ? 1.f : 0.f;
}

// ------- Kernel 2: per (b,s): h = x(256x64) @ W(64x64), e1/e2 dots -----------
__global__ __launch_bounds__(256) void k_h(
    const float* __restrict__ x, const float* __restrict__ Wd,
    const float* __restrict__ Aa,
    float* __restrict__ Hh, float* __restrict__ E1, float* __restrict__ E2)
{
    const int bs = blockIdx.x;
    const int n = threadIdx.x;
    __shared__ float Ws[IF * OF];      // 16 KB, [i][o]
    __shared__ float a1s[OF], a2s[OF];
    for (int idx = n; idx < IF * OF; idx += 256)
        Ws[idx] = Wd[(size_t)bs * 4096 + idx];
    if (n < 64) a1s[n] = Aa[(size_t)bs * 128 + n];
    else if (n < 128) a2s[n - 64] = Aa[(size_t)bs * 128 + n];
    __syncthreads();

    // x row for this thread, in registers (static indexing only)
    float4 xr[16];
    const float4* xp = (const float4*)(x + (size_t)(bs * NN + n) * IF);
#pragma unroll
    for (int u = 0; u < 16; ++u) xr[u] = xp[u];

    float4 acc[16];
#pragma unroll
    for (int u = 0; u < 16; ++u) acc[u] = make_float4(0.f, 0.f, 0.f, 0.f);

#pragma unroll
    for (int i4 = 0; i4 < 16; ++i4) {
        const float xc[4] = { xr[i4].x, xr[i4].y, xr[i4].z, xr[i4].w };
#pragma unroll
        for (int c = 0; c < 4; ++c) {
            const float xv = xc[c];
            const float4* wrow = (const float4*)&Ws[(i4 * 4 + c) * OF];
#pragma unroll
            for (int u = 0; u < 16; ++u) {
                acc[u].x = fmaf(xv, wrow[u].x, acc[u].x);
                acc[u].y = fmaf(xv, wrow[u].y, acc[u].y);
                acc[u].z = fmaf(xv, wrow[u].z, acc[u].z);
                acc[u].w = fmaf(xv, wrow[u].w, acc[u].w);
            }
        }
    }

    float e1v = 0.f, e2v = 0.f;
#pragma unroll
    for (int u = 0; u < 16; ++u) {
        e1v += acc[u].x * a1s[4 * u + 0] + acc[u].y * a1s[4 * u + 1]
             + acc[u].z * a1s[4 * u + 2] + acc[u].w * a1s[4 * u + 3];
        e2v += acc[u].x * a2s[4 * u + 0] + acc[u].y * a2s[4 * u + 1]
             + acc[u].z * a2s[4 * u + 2] + acc[u].w * a2s[4 * u + 3];
    }

    float4* hp = (float4*)(Hh + (size_t)(bs * NN + n) * OF);
#pragma unroll
    for (int u = 0; u < 16; ++u) hp[u] = acc[u];
    E1[bs * NN + n] = e1v;
    E2[bs * NN + n] = e2v;
}

// ------ Kernel 3a: softmax-over-s stats M,R per (b,i,j), stored [b][j][i] ----
__global__ __launch_bounds__(256) void k_softstats(
    const float* __restrict__ E1, const float* __restrict__ E2,
    float* __restrict__ MT, float* __restrict__ RT)
{
    const int bid = blockIdx.x;        // b*256 + j
    const int b = bid >> 8, j = bid & 255;
    const int t = threadIdx.x;         // i
    __shared__ float e1t[SS][NN];      // 64 KB
    __shared__ float e2c[SS];
    for (int s = 0; s < SS; ++s)
        e1t[s][t] = E1[(size_t)((b * SS + s) * NN) + t];
    if (t < SS) e2c[t] = E2[(size_t)((b * SS + t) * NN) + j];
    __syncthreads();

    float mx = -3.0e38f;
#pragma unroll
    for (int s = 0; s < SS; ++s) {
        float v = e1t[s][t] + e2c[s];
        v = (v >= 0.f) ? v : ALPHA * v;
        mx = fmaxf(mx, v);
    }
    float sum = 0.f;
#pragma unroll
    for (int s = 0; s < SS; ++s) {
        float v = e1t[s][t] + e2c[s];
        v = (v >= 0.f) ? v : ALPHA * v;
        sum += __expf(v - mx);
    }
    MT[(size_t)bid * NN + t] = mx;
    RT[(size_t)bid * NN + t] = 1.f / sum;
}

// ------ Kernel 3b: per (b,s): h' = A(256x256)@h(256x64), A on the fly, elu ---
__global__ __launch_bounds__(256) void k_attn(
    const float* __restrict__ Hh, const float* __restrict__ E1,
    const float* __restrict__ E2, const float* __restrict__ MT,
    const float* __restrict__ RT, const float* __restrict__ maskT,
    float* __restrict__ out)
{
    const int bs = blockIdx.x;        // b*64 + s
    const int b = bs >> 6;
    const int t = threadIdx.x;        // i (output row)
    __shared__ float hs[NN * OF];     // 64 KB, [j][o]
    __shared__ float e2s[NN];
    {
        const float4* src = (const float4*)(Hh + (size_t)bs * NN * OF);
        float4* dst = (float4*)hs;
        for (int idx = t; idx < NN * OF / 4; idx += 256) dst[idx] = src[idx];
    }
    e2s[t] = E2[bs * NN + t];
    const float ei = E1[bs * NN + t];
    __syncthreads();

    float4 acc[16];
#pragma unroll
    for (int u = 0; u < 16; ++u) acc[u] = make_float4(0.f, 0.f, 0.f, 0.f);

    const size_t mbase = (size_t)(b * NN) * NN + t;
#pragma unroll 2
    for (int j = 0; j < NN; ++j) {
        const float mk = maskT[j * NN + t];           // coalesced
        const float Mv = MT[mbase + (size_t)j * NN];  // coalesced
        const float Rv = RT[mbase + (size_t)j * NN];  // coalesced
        float v = ei + e2s[j];
        v = (v >= 0.f) ? v : ALPHA * v;
        // masked (i,j): softmax over s of constant NEG -> exactly 1/64
        const float attn = (mk > 0.f) ? __expf(v - Mv) * Rv : 0.015625f;
        const float4* hj = (const float4*)&hs[j * OF]; // broadcast reads
#pragma unroll
        for (int u = 0; u < 16; ++u) {
            acc[u].x = fmaf(attn, hj[u].x, acc[u].x);
            acc[u].y = fmaf(attn, hj[u].y, acc[u].y);
            acc[u].z = fmaf(attn, hj[u].z, acc[u].z);
            acc[u].w = fmaf(attn, hj[u].w, acc[u].w);
        }
    }

    float4* op = (float4*)(out + (size_t)(bs * NN + t) * OF);
#pragma unroll
    for (int u = 0; u < 16; ++u) {
        float4 r = acc[u];
        r.x = (r.x > 0.f) ? r.x : (__expf(r.x) - 1.f);
        r.y = (r.y > 0.f) ? r.y : (__expf(r.y) - 1.f);
        r.z = (r.z > 0.f) ? r.z : (__expf(r.z) - 1.f);
        r.w = (r.w > 0.f) ? r.w : (__expf(r.w) - 1.f);
        op[u] = r;
    }
}

extern "C" void kernel_launch(void* const* d_in, const int* in_sizes, int n_in,
                              void* d_out, int out_size, void* d_ws, size_t ws_size,
                              hipStream_t stream)
{
    const float* hyper = (const float*)d_in[0];
    const float* x     = (const float*)d_in[1];
    const int*   Adj   = (const int*)d_in[2];
    const float* w1    = (const float*)d_in[3];
    const float* b1    = (const float*)d_in[4];
    const float* w2    = (const float*)d_in[5];
    const float* b2    = (const float*)d_in[6];
    const float* aw1   = (const float*)d_in[7];
    const float* ab1   = (const float*)d_in[8];
    const float* aw2   = (const float*)d_in[9];
    const float* ab2   = (const float*)d_in[10];
    float* out = (float*)d_out;

    float* ws    = (float*)d_ws;
    float* Wd    = ws;                  // 512*4096      = 2097152
    float* Aa    = Wd + 2097152;        // 512*128       = 65536
    float* Hh    = Aa + 65536;          // 512*256*64    = 8388608
    float* E1    = Hh + 8388608;        // 512*256       = 131072
    float* E2    = E1 + 131072;         // 512*256       = 131072
    float* MT    = E2 + 131072;         // 8*256*256     = 524288
    float* RT    = MT + 524288;         // 8*256*256     = 524288
    float* maskT = RT + 524288;         // 256*256       = 65536
    // total: 11,927,552 floats = 45.5 MB

    k_hyper<<<dim3(128), dim3(256), 0, stream>>>(hyper, w1, b1, w2, b2,
                                                 aw1, ab1, aw2, ab2, Wd, Aa);
    k_maskT<<<dim3(256), dim3(256), 0, stream>>>(Adj, maskT);
    k_h<<<dim3(512), dim3(256), 0, stream>>>(x, Wd, Aa, Hh, E1, E2);
    k_softstats<<<dim3(2048), dim3(256), 0, stream>>>(E1, E2, MT, RT);
    k_attn<<<dim3(512), dim3(256), 0, stream>>>(Hh, E1, E2, MT, RT, maskT, out);
}

// Round 3
// 212.642 us; speedup vs baseline: 1.5034x; 1.5034x over previous
//
#include <hip/hip_runtime.h>
#include <math.h>

#define BB 8
#define SS 64
#define NN 256
#define ST 128
#define IF 64
#define OF 64
#define H1 32
#define ALPHA 0.2f
#define JC 8   // j-chunk size in k_attn (stats prefetch granularity)

// ---------------- Kernel 1: hyper MLPs -> W (512x4096), a (512x128) ----------
__global__ __launch_bounds__(256) void k_hyper(
    const float* __restrict__ hyper,
    const float* __restrict__ w1, const float* __restrict__ b1,
    const float* __restrict__ w2, const float* __restrict__ b2,
    const float* __restrict__ aw1, const float* __restrict__ ab1,
    const float* __restrict__ aw2, const float* __restrict__ ab2,
    float* __restrict__ Wd, float* __restrict__ Aa)
{
    const int t = threadIdx.x;
    const int bs0 = blockIdx.x * 4;
    __shared__ float hy[4][ST];
    __shared__ float hdn[4][H1];
    __shared__ float hda[4][H1];
    for (int idx = t; idx < 4 * ST; idx += 256)
        hy[idx >> 7][idx & 127] = hyper[(size_t)bs0 * ST + idx];
    __syncthreads();
    if (t < 128) {
        const int q = t >> 5, c = t & 31;
        float acc = b1[c];
        for (int k = 0; k < ST; ++k) acc = fmaf(hy[q][k], w1[k * H1 + c], acc);
        hdn[q][c] = fmaxf(acc, 0.f);
    } else {
        const int tt = t - 128;
        const int q = tt >> 5, c = tt & 31;
        float acc = ab1[c];
        for (int k = 0; k < ST; ++k) acc = fmaf(hy[q][k], aw1[k * H1 + c], acc);
        hda[q][c] = fmaxf(acc, 0.f);
    }
    __syncthreads();
    for (int e = t; e < 4096; e += 256) {
        const float base = b2[e];
        float a0 = base, a1 = base, a2 = base, a3 = base;
        for (int k = 0; k < H1; ++k) {
            const float wv = w2[k * 4096 + e];
            a0 = fmaf(hdn[0][k], wv, a0);
            a1 = fmaf(hdn[1][k], wv, a1);
            a2 = fmaf(hdn[2][k], wv, a2);
            a3 = fmaf(hdn[3][k], wv, a3);
        }
        Wd[(size_t)(bs0 + 0) * 4096 + e] = fabsf(a0);
        Wd[(size_t)(bs0 + 1) * 4096 + e] = fabsf(a1);
        Wd[(size_t)(bs0 + 2) * 4096 + e] = fabsf(a2);
        Wd[(size_t)(bs0 + 3) * 4096 + e] = fabsf(a3);
    }
    if (t < 128) {
        const float base = ab2[t];
        float a0 = base, a1 = base, a2 = base, a3 = base;
        for (int k = 0; k < H1; ++k) {
            const float wv = aw2[k * 128 + t];
            a0 = fmaf(hda[0][k], wv, a0);
            a1 = fmaf(hda[1][k], wv, a1);
            a2 = fmaf(hda[2][k], wv, a2);
            a3 = fmaf(hda[3][k], wv, a3);
        }
        Aa[(size_t)(bs0 + 0) * 128 + t] = fabsf(a0);
        Aa[(size_t)(bs0 + 1) * 128 + t] = fabsf(a1);
        Aa[(size_t)(bs0 + 2) * 128 + t] = fabsf(a2);
        Aa[(size_t)(bs0 + 3) * 128 + t] = fabsf(a3);
    }
}

// ------------- transpose Adj to float mask [j][i] ----------------------------
__global__ void k_maskT(const int* __restrict__ Adj, float* __restrict__ maskT)
{
    const int i = blockIdx.x, j = threadIdx.x;
    maskT[j * NN + i] = (Adj[i * NN + j] > 0) ? 1.f : 0.f;
}

// ------- Kernel 2: per (b,s): h = x(256x64) @ W(64x64), e1/e2 dots -----------
__global__ __launch_bounds__(256) void k_h(
    const float* __restrict__ x, const float* __restrict__ Wd,
    const float* __restrict__ Aa,
    float* __restrict__ Hh, float* __restrict__ E1, float* __restrict__ E2)
{
    const int bs = blockIdx.x;
    const int n = threadIdx.x;
    __shared__ float Ws[IF * OF];
    __shared__ float a1s[OF], a2s[OF];
    for (int idx = n; idx < IF * OF; idx += 256)
        Ws[idx] = Wd[(size_t)bs * 4096 + idx];
    if (n < 64) a1s[n] = Aa[(size_t)bs * 128 + n];
    else if (n < 128) a2s[n - 64] = Aa[(size_t)bs * 128 + n];
    __syncthreads();

    float4 xr[16];
    const float4* xp = (const float4*)(x + (size_t)(bs * NN + n) * IF);
#pragma unroll
    for (int u = 0; u < 16; ++u) xr[u] = xp[u];

    float4 acc[16];
#pragma unroll
    for (int u = 0; u < 16; ++u) acc[u] = make_float4(0.f, 0.f, 0.f, 0.f);

#pragma unroll
    for (int i4 = 0; i4 < 16; ++i4) {
        const float xc[4] = { xr[i4].x, xr[i4].y, xr[i4].z, xr[i4].w };
#pragma unroll
        for (int c = 0; c < 4; ++c) {
            const float xv = xc[c];
            const float4* wrow = (const float4*)&Ws[(i4 * 4 + c) * OF];
#pragma unroll
            for (int u = 0; u < 16; ++u) {
                acc[u].x = fmaf(xv, wrow[u].x, acc[u].x);
                acc[u].y = fmaf(xv, wrow[u].y, acc[u].y);
                acc[u].z = fmaf(xv, wrow[u].z, acc[u].z);
                acc[u].w = fmaf(xv, wrow[u].w, acc[u].w);
            }
        }
    }

    float e1v = 0.f, e2v = 0.f;
#pragma unroll
    for (int u = 0; u < 16; ++u) {
        e1v += acc[u].x * a1s[4 * u + 0] + acc[u].y * a1s[4 * u + 1]
             + acc[u].z * a1s[4 * u + 2] + acc[u].w * a1s[4 * u + 3];
        e2v += acc[u].x * a2s[4 * u + 0] + acc[u].y * a2s[4 * u + 1]
             + acc[u].z * a2s[4 * u + 2] + acc[u].w * a2s[4 * u + 3];
    }

    float4* hp = (float4*)(Hh + (size_t)(bs * NN + n) * OF);
#pragma unroll
    for (int u = 0; u < 16; ++u) hp[u] = acc[u];
    E1[bs * NN + n] = e1v;
    E2[bs * NN + n] = e2v;
}

// ------ Kernel 3a: softmax-over-s stats per (b,i,j) stored [b][j][i] ---------
// RT sign encodes the adjacency mask: RT < 0  =>  masked, attn == -RT == 1/64.
__global__ __launch_bounds__(256) void k_softstats(
    const float* __restrict__ E1, const float* __restrict__ E2,
    const float* __restrict__ maskT,
    float* __restrict__ MT, float* __restrict__ RT)
{
    const int bid = blockIdx.x;        // b*256 + j
    const int b = bid >> 8, j = bid & 255;
    const int t = threadIdx.x;         // i
    __shared__ float e1t[SS][NN];
    __shared__ float e2c[SS];
    for (int s = 0; s < SS; ++s)
        e1t[s][t] = E1[(size_t)((b * SS + s) * NN) + t];
    if (t < SS) e2c[t] = E2[(size_t)((b * SS + t) * NN) + j];
    __syncthreads();

    float mx = -3.0e38f;
#pragma unroll
    for (int s = 0; s < SS; ++s) {
        float v = e1t[s][t] + e2c[s];
        v = (v >= 0.f) ? v : ALPHA * v;
        mx = fmaxf(mx, v);
    }
    float sum = 0.f;
#pragma unroll
    for (int s = 0; s < SS; ++s) {
        float v = e1t[s][t] + e2c[s];
        v = (v >= 0.f) ? v : ALPHA * v;
        sum += __expf(v - mx);
    }
    const float mk = maskT[j * NN + t];
    MT[(size_t)bid * NN + t] = mx;
    RT[(size_t)bid * NN + t] = (mk > 0.f) ? (1.f / sum) : -0.015625f;
}

// ------ Kernel 3b: per (b,s): h' = A(256x256)@h(256x64), 8x8 register tiles --
// Attention row i is computed by thread i and distributed to its 8-lane
// consumer group via __shfl (intra-wave by construction: consumers of row i
// are threads (i&~7)..(i|7)). No LDS tile, no barriers in the K-loop.
__global__ __launch_bounds__(256) void k_attn(
    const float* __restrict__ Hh, const float* __restrict__ E1,
    const float* __restrict__ E2, const float* __restrict__ MT,
    const float* __restrict__ RT, float* __restrict__ out)
{
    const int bs = blockIdx.x;        // b*64 + s
    const int b = bs >> 6;
    const int tid = threadIdx.x;
    const int it = tid >> 3;          // rows it*8 .. it*8+7
    const int ot = tid & 7;           // cols ot*4..+3 and 32+ot*4..+3
    const int lb = (tid & 63) & ~7;   // wave-lane base of this 8-lane group

    __shared__ float Hs[NN * OF];     // 64 KB, [j][o]
    __shared__ float e2s[NN];         // 1 KB

    // prefetch chunk-0 stats (for row i = tid) while staging runs
    const size_t mbase = (size_t)(b * NN) * NN + tid;
    float Mv[JC], Rv[JC];
#pragma unroll
    for (int jj = 0; jj < JC; ++jj) {
        Mv[jj] = MT[mbase + (size_t)jj * NN];
        Rv[jj] = RT[mbase + (size_t)jj * NN];
    }
    const float ei = E1[bs * NN + tid];
    e2s[tid] = E2[bs * NN + tid];
    {
        const float4* src = (const float4*)(Hh + (size_t)bs * NN * OF);
        float4* dst = (float4*)Hs;
        for (int idx = tid; idx < NN * OF / 4; idx += 256) dst[idx] = src[idx];
    }
    __syncthreads();   // the only barrier: Hs/e2s staged

    float4 acc[8][2];
#pragma unroll
    for (int r = 0; r < 8; ++r) {
        acc[r][0] = make_float4(0.f, 0.f, 0.f, 0.f);
        acc[r][1] = make_float4(0.f, 0.f, 0.f, 0.f);
    }

    for (int ch = 0; ch < NN / JC; ++ch) {
        // attn values for (row i = tid, j = ch*JC + jj), thread-local
        float av[JC];
#pragma unroll
        for (int jj = 0; jj < JC; ++jj) {
            float v = ei + e2s[ch * JC + jj];
            v = (v >= 0.f) ? v : ALPHA * v;
            av[jj] = (Rv[jj] < 0.f) ? -Rv[jj] : __expf(v - Mv[jj]) * Rv[jj];
        }
        // prefetch next chunk's stats (in flight during GEMM)
        if (ch < NN / JC - 1) {
            const size_t nb = mbase + (size_t)(ch + 1) * JC * NN;
#pragma unroll
            for (int jj = 0; jj < JC; ++jj) {
                Mv[jj] = MT[nb + (size_t)jj * NN];
                Rv[jj] = RT[nb + (size_t)jj * NN];
            }
        }
        // GEMM: C(256x64) += A_chunk(256x8) @ H_chunk(8x64); A via shuffles
#pragma unroll
        for (int jj = 0; jj < JC; ++jj) {
            const int j = ch * JC + jj;
            const float4 h0 = *(const float4*)&Hs[j * OF + ot * 4];
            const float4 h1 = *(const float4*)&Hs[j * OF + 32 + ot * 4];
#pragma unroll
            for (int r = 0; r < 8; ++r) {
                const float ar = __shfl(av[jj], lb + r, 64);
                acc[r][0].x = fmaf(ar, h0.x, acc[r][0].x);
                acc[r][0].y = fmaf(ar, h0.y, acc[r][0].y);
                acc[r][0].z = fmaf(ar, h0.z, acc[r][0].z);
                acc[r][0].w = fmaf(ar, h0.w, acc[r][0].w);
                acc[r][1].x = fmaf(ar, h1.x, acc[r][1].x);
                acc[r][1].y = fmaf(ar, h1.y, acc[r][1].y);
                acc[r][1].z = fmaf(ar, h1.z, acc[r][1].z);
                acc[r][1].w = fmaf(ar, h1.w, acc[r][1].w);
            }
        }
    }

    // ---- epilogue: elu + store
    const size_t obase = (size_t)bs * NN * OF;
#pragma unroll
    for (int r = 0; r < 8; ++r) {
        const int i = it * 8 + r;
        float4 v0 = acc[r][0], v1 = acc[r][1];
        v0.x = (v0.x > 0.f) ? v0.x : (__expf(v0.x) - 1.f);
        v0.y = (v0.y > 0.f) ? v0.y : (__expf(v0.y) - 1.f);
        v0.z = (v0.z > 0.f) ? v0.z : (__expf(v0.z) - 1.f);
        v0.w = (v0.w > 0.f) ? v0.w : (__expf(v0.w) - 1.f);
        v1.x = (v1.x > 0.f) ? v1.x : (__expf(v1.x) - 1.f);
        v1.y = (v1.y > 0.f) ? v1.y : (__expf(v1.y) - 1.f);
        v1.z = (v1.z > 0.f) ? v1.z : (__expf(v1.z) - 1.f);
        v1.w = (v1.w > 0.f) ? v1.w : (__expf(v1.w) - 1.f);
        *(float4*)&out[obase + (size_t)i * OF + ot * 4] = v0;
        *(float4*)&out[obase + (size_t)i * OF + 32 + ot * 4] = v1;
    }
}

extern "C" void kernel_launch(void* const* d_in, const int* in_sizes, int n_in,
                              void* d_out, int out_size, void* d_ws, size_t ws_size,
                              hipStream_t stream)
{
    const float* hyper = (const float*)d_in[0];
    const float* x     = (const float*)d_in[1];
    const int*   Adj   = (const int*)d_in[2];
    const float* w1    = (const float*)d_in[3];
    const float* b1    = (const float*)d_in[4];
    const float* w2    = (const float*)d_in[5];
    const float* b2    = (const float*)d_in[6];
    const float* aw1   = (const float*)d_in[7];
    const float* ab1   = (const float*)d_in[8];
    const float* aw2   = (const float*)d_in[9];
    const float* ab2   = (const float*)d_in[10];
    float* out = (float*)d_out;

    float* ws    = (float*)d_ws;
    float* Wd    = ws;                  // 512*4096
    float* Aa    = Wd + 2097152;        // 512*128
    float* Hh    = Aa + 65536;          // 512*256*64
    float* E1    = Hh + 8388608;        // 512*256
    float* E2    = E1 + 131072;         // 512*256
    float* MT    = E2 + 131072;         // 8*256*256
    float* RT    = MT + 524288;         // 8*256*256
    float* maskT = RT + 524288;         // 256*256

    k_hyper<<<dim3(128), dim3(256), 0, stream>>>(hyper, w1, b1, w2, b2,
                                                 aw1, ab1, aw2, ab2, Wd, Aa);
    k_maskT<<<dim3(256), dim3(256), 0, stream>>>(Adj, maskT);
    k_h<<<dim3(512), dim3(256), 0, stream>>>(x, Wd, Aa, Hh, E1, E2);
    k_softstats<<<dim3(2048), dim3(256), 0, stream>>>(E1, E2, maskT, MT, RT);
    k_attn<<<dim3(512), dim3(256), 0, stream>>>(Hh, E1, E2, MT, RT, out);
}

// Round 4
// 162.009 us; speedup vs baseline: 1.9732x; 1.3125x over previous
//
#include <hip/hip_runtime.h>
#include <hip/hip_bf16.h>
#include <math.h>

#define BB 8
#define SS 64
#define NN 256
#define ST 128
#define IF 64
#define OF 64
#define H1 32
#define ALPHA 0.2f

typedef short short8 __attribute__((ext_vector_type(8)));
typedef float f32x4 __attribute__((ext_vector_type(4)));
typedef unsigned short ushort_t;

static __device__ __forceinline__ ushort_t f2bf(float f) {
    __hip_bfloat16 h = __float2bfloat16(f);
    return *reinterpret_cast<ushort_t*>(&h);
}

// ---------------- Kernel 1: hyper MLPs -> W (512x4096), a (512x128) ----------
__global__ __launch_bounds__(256) void k_hyper(
    const float* __restrict__ hyper,
    const float* __restrict__ w1, const float* __restrict__ b1,
    const float* __restrict__ w2, const float* __restrict__ b2,
    const float* __restrict__ aw1, const float* __restrict__ ab1,
    const float* __restrict__ aw2, const float* __restrict__ ab2,
    float* __restrict__ Wd, float* __restrict__ Aa)
{
    const int t = threadIdx.x;
    const int bs0 = blockIdx.x * 4;
    __shared__ float hy[4][ST];
    __shared__ float hdn[4][H1];
    __shared__ float hda[4][H1];
    for (int idx = t; idx < 4 * ST; idx += 256)
        hy[idx >> 7][idx & 127] = hyper[(size_t)bs0 * ST + idx];
    __syncthreads();
    if (t < 128) {
        const int q = t >> 5, c = t & 31;
        float acc = b1[c];
        for (int k = 0; k < ST; ++k) acc = fmaf(hy[q][k], w1[k * H1 + c], acc);
        hdn[q][c] = fmaxf(acc, 0.f);
    } else {
        const int tt = t - 128;
        const int q = tt >> 5, c = tt & 31;
        float acc = ab1[c];
        for (int k = 0; k < ST; ++k) acc = fmaf(hy[q][k], aw1[k * H1 + c], acc);
        hda[q][c] = fmaxf(acc, 0.f);
    }
    __syncthreads();
    for (int e = t; e < 4096; e += 256) {
        const float base = b2[e];
        float a0 = base, a1 = base, a2 = base, a3 = base;
        for (int k = 0; k < H1; ++k) {
            const float wv = w2[k * 4096 + e];
            a0 = fmaf(hdn[0][k], wv, a0);
            a1 = fmaf(hdn[1][k], wv, a1);
            a2 = fmaf(hdn[2][k], wv, a2);
            a3 = fmaf(hdn[3][k], wv, a3);
        }
        Wd[(size_t)(bs0 + 0) * 4096 + e] = fabsf(a0);
        Wd[(size_t)(bs0 + 1) * 4096 + e] = fabsf(a1);
        Wd[(size_t)(bs0 + 2) * 4096 + e] = fabsf(a2);
        Wd[(size_t)(bs0 + 3) * 4096 + e] = fabsf(a3);
    }
    if (t < 128) {
        const float base = ab2[t];
        float a0 = base, a1 = base, a2 = base, a3 = base;
        for (int k = 0; k < H1; ++k) {
            const float wv = aw2[k * 128 + t];
            a0 = fmaf(hda[0][k], wv, a0);
            a1 = fmaf(hda[1][k], wv, a1);
            a2 = fmaf(hda[2][k], wv, a2);
            a3 = fmaf(hda[3][k], wv, a3);
        }
        Aa[(size_t)(bs0 + 0) * 128 + t] = fabsf(a0);
        Aa[(size_t)(bs0 + 1) * 128 + t] = fabsf(a1);
        Aa[(size_t)(bs0 + 2) * 128 + t] = fabsf(a2);
        Aa[(size_t)(bs0 + 3) * 128 + t] = fabsf(a3);
    }
}

// ------------- transpose Adj to float mask [j][i] ----------------------------
__global__ void k_maskT(const int* __restrict__ Adj, float* __restrict__ maskT)
{
    const int i = blockIdx.x, j = threadIdx.x;
    maskT[j * NN + i] = (Adj[i * NN + j] > 0) ? 1.f : 0.f;
}

// ------- Kernel 2: per (b,s): h = x(256x64)@W(64x64) 8x8 reg tiles -----------
// Writes h as bf16 TRANSPOSED: HbT[bs][o][n]  (B^T layout for the MFMA kernel)
// e1/e2 (f32) via __shfl_xor reduction over the 8-lane column group.
__global__ __launch_bounds__(256) void k_h(
    const float* __restrict__ x, const float* __restrict__ Wd,
    const float* __restrict__ Aa,
    ushort_t* __restrict__ HbT, float* __restrict__ E1, float* __restrict__ E2)
{
    const int bs = blockIdx.x;
    const int tid = threadIdx.x;
    const int nt = tid >> 3;          // rows nt*8 .. nt*8+7
    const int ot = tid & 7;           // cols ot*8 .. ot*8+7
    __shared__ float Wl[IF * OF];     // 16 KB [k][o]
    __shared__ float a1s[OF], a2s[OF];
    {
        const float4* src = (const float4*)(Wd + (size_t)bs * 4096);
        float4* dst = (float4*)Wl;
        for (int p = 0; p < 4; ++p) dst[tid + p * 256] = src[tid + p * 256];
        if (tid < 64) a1s[tid] = Aa[(size_t)bs * 128 + tid];
        else if (tid < 128) a2s[tid - 64] = Aa[(size_t)bs * 128 + tid];
    }
    __syncthreads();

    const float4* xb = (const float4*)(x + ((size_t)bs * NN + nt * 8) * IF);
    float acc[8][8];
#pragma unroll
    for (int r = 0; r < 8; ++r)
#pragma unroll
        for (int c = 0; c < 8; ++c) acc[r][c] = 0.f;

#pragma unroll
    for (int kq = 0; kq < 16; ++kq) {
        float4 xv[8];
#pragma unroll
        for (int r = 0; r < 8; ++r) xv[r] = xb[r * 16 + kq];  // global, wave-merged
#pragma unroll
        for (int c = 0; c < 4; ++c) {
            const int k = kq * 4 + c;
            const float4 w0 = *(const float4*)&Wl[k * OF + ot * 8];
            const float4 w1 = *(const float4*)&Wl[k * OF + ot * 8 + 4];
#pragma unroll
            for (int r = 0; r < 8; ++r) {
                const float xs = (c == 0) ? xv[r].x : (c == 1) ? xv[r].y
                               : (c == 2) ? xv[r].z : xv[r].w;
                acc[r][0] = fmaf(xs, w0.x, acc[r][0]);
                acc[r][1] = fmaf(xs, w0.y, acc[r][1]);
                acc[r][2] = fmaf(xs, w0.z, acc[r][2]);
                acc[r][3] = fmaf(xs, w0.w, acc[r][3]);
                acc[r][4] = fmaf(xs, w1.x, acc[r][4]);
                acc[r][5] = fmaf(xs, w1.y, acc[r][5]);
                acc[r][6] = fmaf(xs, w1.z, acc[r][6]);
                acc[r][7] = fmaf(xs, w1.w, acc[r][7]);
            }
        }
    }

    // e1/e2: partial dot over this thread's 8 cols, then xor-reduce over ot
    const float4 av0 = *(const float4*)&a1s[ot * 8];
    const float4 av1 = *(const float4*)&a1s[ot * 8 + 4];
    const float4 bv0 = *(const float4*)&a2s[ot * 8];
    const float4 bv1 = *(const float4*)&a2s[ot * 8 + 4];
    float e1sel = 0.f, e2sel = 0.f;
#pragma unroll
    for (int r = 0; r < 8; ++r) {
        float p1 = acc[r][0]*av0.x + acc[r][1]*av0.y + acc[r][2]*av0.z + acc[r][3]*av0.w
                 + acc[r][4]*av1.x + acc[r][5]*av1.y + acc[r][6]*av1.z + acc[r][7]*av1.w;
        float p2 = acc[r][0]*bv0.x + acc[r][1]*bv0.y + acc[r][2]*bv0.z + acc[r][3]*bv0.w
                 + acc[r][4]*bv1.x + acc[r][5]*bv1.y + acc[r][6]*bv1.z + acc[r][7]*bv1.w;
        p1 += __shfl_xor(p1, 1, 64); p2 += __shfl_xor(p2, 1, 64);
        p1 += __shfl_xor(p1, 2, 64); p2 += __shfl_xor(p2, 2, 64);
        p1 += __shfl_xor(p1, 4, 64); p2 += __shfl_xor(p2, 4, 64);
        if (ot == r) { e1sel = p1; e2sel = p2; }   // static unrolled select
    }
    E1[(size_t)bs * NN + tid] = e1sel;   // row nt*8+ot == tid
    E2[(size_t)bs * NN + tid] = e2sel;

    // HbT[bs][o][n]: for each of my 8 cols, pack my 8 rows as bf16 (16B store)
    ushort_t* hb = HbT + (size_t)bs * (OF * NN);
#pragma unroll
    for (int c = 0; c < 8; ++c) {
        short8 pk;
#pragma unroll
        for (int r = 0; r < 8; ++r) pk[r] = (short)f2bf(acc[r][c]);
        *(short8*)(hb + (size_t)(ot * 8 + c) * NN + nt * 8) = pk;
    }
}

// ------ Kernel 3a: softmax-over-s stats per (b,i,j) stored [b][j][i] ---------
// RT sign encodes the adjacency mask: RT < 0  =>  masked, attn == -RT == 1/64.
__global__ __launch_bounds__(256) void k_softstats(
    const float* __restrict__ E1, const float* __restrict__ E2,
    const float* __restrict__ maskT,
    float* __restrict__ MT, float* __restrict__ RT)
{
    const int bid = blockIdx.x;        // b*256 + j
    const int b = bid >> 8, j = bid & 255;
    const int t = threadIdx.x;         // i
    __shared__ float e1t[SS][NN];
    __shared__ float e2c[SS];
    for (int s = 0; s < SS; ++s)
        e1t[s][t] = E1[(size_t)((b * SS + s) * NN) + t];
    if (t < SS) e2c[t] = E2[(size_t)((b * SS + t) * NN) + j];
    __syncthreads();

    float mx = -3.0e38f;
#pragma unroll
    for (int s = 0; s < SS; ++s) {
        float v = e1t[s][t] + e2c[s];
        v = (v >= 0.f) ? v : ALPHA * v;
        mx = fmaxf(mx, v);
    }
    float sum = 0.f;
#pragma unroll
    for (int s = 0; s < SS; ++s) {
        float v = e1t[s][t] + e2c[s];
        v = (v >= 0.f) ? v : ALPHA * v;
        sum += __expf(v - mx);
    }
    const float mk = maskT[j * NN + t];
    MT[(size_t)bid * NN + t] = mx;
    RT[(size_t)bid * NN + t] = (mk > 0.f) ? (1.f / sum) : -0.015625f;
}

// ------ Kernel 3b: per (b,s): O = ELU(A(256x256) @ H(256x64)) via bf16 MFMA --
// A built on the fly per 64-col chunk into swizzled LDS (bf16, row-major [i][k]).
// H^T staged once from HbT into swizzled LDS (bf16, [o][j] = B^T row-major).
// mfma_f32_16x16x32_bf16; C/D: col=lane&15, row=(lane>>4)*4+reg (m89-verified).
__global__ __launch_bounds__(256) void k_attn(
    const ushort_t* __restrict__ HbT, const float* __restrict__ E1,
    const float* __restrict__ E2, const float* __restrict__ MT,
    const float* __restrict__ RT, float* __restrict__ out)
{
    const int bs = blockIdx.x;        // b*64 + s
    const int b = bs >> 6;
    const int tid = threadIdx.x;
    const int wid = tid >> 6;         // wave 0..3 -> output rows wid*64..+63
    const int lane = tid & 63;

    __shared__ ushort_t HT[OF * NN];  // 32 KB  B^T [o][j], XOR-swizzled
    __shared__ ushort_t Als[NN * 64]; // 32 KB  A-chunk [i][jj], XOR-swizzled
    __shared__ float e2s[NN];

    // ---- stage H^T (bf16) with st-swizzle: byte ^= (o&7)<<4  (512B rows)
    {
        const short8* src = (const short8*)(HbT + (size_t)bs * (OF * NN));
        char* dst = (char*)HT;
#pragma unroll
        for (int p = 0; p < 8; ++p) {
            const int idx = tid + p * 256;        // 16B units, 2048 total
            const int byte = idx * 16;
            const int o = byte >> 9;
            *(short8*)(dst + (byte ^ ((o & 7) << 4))) = src[idx];
        }
    }
    e2s[tid] = E2[(size_t)bs * NN + tid];
    const float ei = E1[(size_t)bs * NN + tid];
    __syncthreads();

    f32x4 acc[4][4];
#pragma unroll
    for (int mt = 0; mt < 4; ++mt)
#pragma unroll
        for (int nt = 0; nt < 4; ++nt) acc[mt][nt] = (f32x4){0.f, 0.f, 0.f, 0.f};

    const char* Ab = (const char*)Als;
    const char* Hb = (const char*)HT;
    const size_t mrbase = ((size_t)b * NN) * NN + tid;

    for (int ch = 0; ch < 4; ++ch) {
        // ---- build A-chunk: thread = row i=tid, cols j = ch*64 .. +63
        char* Aw = (char*)Als;
#pragma unroll
        for (int g = 0; g < 8; ++g) {
            float mv[8], rv[8];
#pragma unroll
            for (int q = 0; q < 8; ++q) {
                const size_t mo = mrbase + (size_t)(ch * 64 + g * 8 + q) * NN;
                mv[q] = MT[mo];
                rv[q] = RT[mo];
            }
            short8 pk;
#pragma unroll
            for (int q = 0; q < 8; ++q) {
                float v = ei + e2s[ch * 64 + g * 8 + q];
                v = (v >= 0.f) ? v : ALPHA * v;
                const float a = (rv[q] < 0.f) ? -rv[q] : __expf(v - mv[q]) * rv[q];
                pk[q] = (short)f2bf(a);
            }
            const int byte = tid * 128 + g * 16;             // row i=tid, 128B rows
            *(short8*)(Aw + (byte ^ ((tid & 7) << 4))) = pk;
        }
        __syncthreads();   // A-chunk ready

        // ---- MFMA: per wave, rows wid*64..+63 x cols 0..63, K = 64 (2 steps)
        short8 af[4][2], bf[4][2];
#pragma unroll
        for (int mt = 0; mt < 4; ++mt) {
            const int row = wid * 64 + mt * 16 + (lane & 15);
#pragma unroll
            for (int ks = 0; ks < 2; ++ks) {
                const int byte = row * 128 + (ks * 32 + ((lane >> 4) * 8)) * 2;
                af[mt][ks] = *(const short8*)(Ab + (byte ^ ((row & 7) << 4)));
            }
        }
#pragma unroll
        for (int nt = 0; nt < 4; ++nt) {
            const int o = nt * 16 + (lane & 15);
#pragma unroll
            for (int ks = 0; ks < 2; ++ks) {
                const int byte = o * 512 + (ch * 64 + ks * 32 + ((lane >> 4) * 8)) * 2;
                bf[nt][ks] = *(const short8*)(Hb + (byte ^ ((o & 7) << 4)));
            }
        }
#pragma unroll
        for (int mt = 0; mt < 4; ++mt)
#pragma unroll
            for (int nt = 0; nt < 4; ++nt) {
                acc[mt][nt] = __builtin_amdgcn_mfma_f32_16x16x32_bf16(
                    af[mt][0], bf[nt][0], acc[mt][nt], 0, 0, 0);
                acc[mt][nt] = __builtin_amdgcn_mfma_f32_16x16x32_bf16(
                    af[mt][1], bf[nt][1], acc[mt][nt], 0, 0, 0);
            }
        __syncthreads();   // done reading A-chunk before next build
    }

    // ---- epilogue: ELU + store f32
    float* ob = out + (size_t)bs * (NN * OF);
#pragma unroll
    for (int mt = 0; mt < 4; ++mt) {
        const int rbase = wid * 64 + mt * 16 + (lane >> 4) * 4;
#pragma unroll
        for (int nt = 0; nt < 4; ++nt) {
            const int o = nt * 16 + (lane & 15);
#pragma unroll
            for (int reg = 0; reg < 4; ++reg) {
                float v = acc[mt][nt][reg];
                v = (v > 0.f) ? v : (__expf(v) - 1.f);
                ob[(size_t)(rbase + reg) * OF + o] = v;
            }
        }
    }
}

extern "C" void kernel_launch(void* const* d_in, const int* in_sizes, int n_in,
                              void* d_out, int out_size, void* d_ws, size_t ws_size,
                              hipStream_t stream)
{
    const float* hyper = (const float*)d_in[0];
    const float* x     = (const float*)d_in[1];
    const int*   Adj   = (const int*)d_in[2];
    const float* w1    = (const float*)d_in[3];
    const float* b1    = (const float*)d_in[4];
    const float* w2    = (const float*)d_in[5];
    const float* b2    = (const float*)d_in[6];
    const float* aw1   = (const float*)d_in[7];
    const float* ab1   = (const float*)d_in[8];
    const float* aw2   = (const float*)d_in[9];
    const float* ab2   = (const float*)d_in[10];
    float* out = (float*)d_out;

    float* ws      = (float*)d_ws;
    float* Wd      = ws;                      // 512*4096            = 2097152 f
    float* Aa      = Wd + 2097152;            // 512*128             = 65536 f
    ushort_t* HbT  = (ushort_t*)(Aa + 65536); // 512*64*256 bf16     = 4194304 f-equiv
    float* E1      = (float*)(HbT + 8388608); // 512*256             = 131072 f
    float* E2      = E1 + 131072;             // 512*256
    float* MT      = E2 + 131072;             // 8*256*256
    float* RT      = MT + 524288;             // 8*256*256
    float* maskT   = RT + 524288;             // 256*256

    k_hyper<<<dim3(128), dim3(256), 0, stream>>>(hyper, w1, b1, w2, b2,
                                                 aw1, ab1, aw2, ab2, Wd, Aa);
    k_maskT<<<dim3(256), dim3(256), 0, stream>>>(Adj, maskT);
    k_h<<<dim3(512), dim3(256), 0, stream>>>(x, Wd, Aa, HbT, E1, E2);
    k_softstats<<<dim3(2048), dim3(256), 0, stream>>>(E1, E2, maskT, MT, RT);
    k_attn<<<dim3(512), dim3(256), 0, stream>>>(HbT, E1, E2, MT, RT, out);
}

// Round 5
// 110.497 us; speedup vs baseline: 2.8931x; 1.4662x over previous
//
#include <hip/hip_runtime.h>
#include <hip/hip_bf16.h>
#include <math.h>

#define BB 8
#define SS 64
#define NN 256
#define ST 128
#define IF 64
#define OF 64
#define H1 32
#define ALPHA 0.2f

typedef short short8 __attribute__((ext_vector_type(8)));
typedef float f32x4 __attribute__((ext_vector_type(4)));
typedef unsigned short ushort_t;

static __device__ __forceinline__ ushort_t f2bf(float f) {
    __hip_bfloat16 h = __float2bfloat16(f);
    return *reinterpret_cast<ushort_t*>(&h);
}

// ---- Kernel 1a: stage-1 MLPs -> Hdn (512x32, ws) and Aa (512x128) ----------
// 4 bs per block, 128 blocks. Threads 0..127: hdn; 128..255: hda.
__global__ __launch_bounds__(256) void k_mlp1(
    const float* __restrict__ hyper,
    const float* __restrict__ w1, const float* __restrict__ b1,
    const float* __restrict__ aw1, const float* __restrict__ ab1,
    const float* __restrict__ aw2, const float* __restrict__ ab2,
    float* __restrict__ Hdn, float* __restrict__ Aa)
{
    const int t = threadIdx.x;
    const int bs0 = blockIdx.x * 4;
    __shared__ float hy[4][ST];      // 2 KB
    __shared__ float hda_s[4][H1];   // 512 B
    for (int idx = t; idx < 4 * ST; idx += 256)
        hy[idx >> 7][idx & 127] = hyper[(size_t)bs0 * ST + idx];
    __syncthreads();
    if (t < 128) {
        const int q = t >> 5, c = t & 31;
        float acc = b1[c];
#pragma unroll 4
        for (int k = 0; k < ST; ++k) acc = fmaf(hy[q][k], w1[k * H1 + c], acc);
        Hdn[(size_t)(bs0 + q) * H1 + c] = fmaxf(acc, 0.f);
    } else {
        const int tt = t - 128;
        const int q = tt >> 5, c = tt & 31;
        float acc = ab1[c];
#pragma unroll 4
        for (int k = 0; k < ST; ++k) acc = fmaf(hy[q][k], aw1[k * H1 + c], acc);
        hda_s[q][c] = fmaxf(acc, 0.f);
    }
    __syncthreads();
    // Aa: 4 bs x 128 outputs = 512, 2 per thread
#pragma unroll
    for (int p = 0; p < 2; ++p) {
        const int idx = t + p * 256;
        const int qq = idx >> 7, cc = idx & 127;
        float a = ab2[cc];
#pragma unroll
        for (int k = 0; k < H1; ++k)
            a = fmaf(hda_s[qq][k], aw2[k * 128 + cc], a);
        Aa[(size_t)(bs0 + qq) * 128 + cc] = fabsf(a);
    }
}

// ---- Kernel 1b: W = abs(Hdn(512x32) @ w2(32x4096) + b2) -> Wd --------------
// Block = (4 bs) x (1024 e). 512 blocks. Thread: 4 e (float4) x 4 bs accs.
__global__ __launch_bounds__(256) void k_w2(
    const float* __restrict__ Hdn, const float* __restrict__ w2,
    const float* __restrict__ b2, float* __restrict__ Wd)
{
    const int t = threadIdx.x;
    const int bs0 = (blockIdx.x >> 2) * 4;
    const int e0 = (blockIdx.x & 3) * 1024;
    __shared__ float hd[4][H1];      // 512 B
    if (t < 128) hd[t >> 5][t & 31] = Hdn[(size_t)bs0 * H1 + t];
    __syncthreads();

    const int e = e0 + t * 4;
    const float4 bb = *(const float4*)&b2[e];
    float4 a0 = bb, a1 = bb, a2 = bb, a3 = bb;
#pragma unroll
    for (int kq = 0; kq < 8; ++kq) {
        const float4 h0 = *(const float4*)&hd[0][kq * 4];
        const float4 h1 = *(const float4*)&hd[1][kq * 4];
        const float4 h2 = *(const float4*)&hd[2][kq * 4];
        const float4 h3 = *(const float4*)&hd[3][kq * 4];
#pragma unroll
        for (int c = 0; c < 4; ++c) {
            const float4 wv = *(const float4*)&w2[(size_t)(kq * 4 + c) * 4096 + e];
            const float s0 = (c == 0) ? h0.x : (c == 1) ? h0.y : (c == 2) ? h0.z : h0.w;
            const float s1 = (c == 0) ? h1.x : (c == 1) ? h1.y : (c == 2) ? h1.z : h1.w;
            const float s2 = (c == 0) ? h2.x : (c == 1) ? h2.y : (c == 2) ? h2.z : h2.w;
            const float s3 = (c == 0) ? h3.x : (c == 1) ? h3.y : (c == 2) ? h3.z : h3.w;
            a0.x = fmaf(s0, wv.x, a0.x); a0.y = fmaf(s0, wv.y, a0.y);
            a0.z = fmaf(s0, wv.z, a0.z); a0.w = fmaf(s0, wv.w, a0.w);
            a1.x = fmaf(s1, wv.x, a1.x); a1.y = fmaf(s1, wv.y, a1.y);
            a1.z = fmaf(s1, wv.z, a1.z); a1.w = fmaf(s1, wv.w, a1.w);
            a2.x = fmaf(s2, wv.x, a2.x); a2.y = fmaf(s2, wv.y, a2.y);
            a2.z = fmaf(s2, wv.z, a2.z); a2.w = fmaf(s2, wv.w, a2.w);
            a3.x = fmaf(s3, wv.x, a3.x); a3.y = fmaf(s3, wv.y, a3.y);
            a3.z = fmaf(s3, wv.z, a3.z); a3.w = fmaf(s3, wv.w, a3.w);
        }
    }
    a0.x = fabsf(a0.x); a0.y = fabsf(a0.y); a0.z = fabsf(a0.z); a0.w = fabsf(a0.w);
    a1.x = fabsf(a1.x); a1.y = fabsf(a1.y); a1.z = fabsf(a1.z); a1.w = fabsf(a1.w);
    a2.x = fabsf(a2.x); a2.y = fabsf(a2.y); a2.z = fabsf(a2.z); a2.w = fabsf(a2.w);
    a3.x = fabsf(a3.x); a3.y = fabsf(a3.y); a3.z = fabsf(a3.z); a3.w = fabsf(a3.w);
    *(float4*)&Wd[(size_t)(bs0 + 0) * 4096 + e] = a0;
    *(float4*)&Wd[(size_t)(bs0 + 1) * 4096 + e] = a1;
    *(float4*)&Wd[(size_t)(bs0 + 2) * 4096 + e] = a2;
    *(float4*)&Wd[(size_t)(bs0 + 3) * 4096 + e] = a3;
}

// ------------- transpose Adj to float mask [j][i] ----------------------------
__global__ void k_maskT(const int* __restrict__ Adj, float* __restrict__ maskT)
{
    const int i = blockIdx.x, j = threadIdx.x;
    maskT[j * NN + i] = (Adj[i * NN + j] > 0) ? 1.f : 0.f;
}

// ------- Kernel 2: per (b,s): h = x(256x64)@W(64x64) 8x8 reg tiles -----------
// Writes h as bf16 TRANSPOSED: HbT[bs][o][n]  (B^T layout for the MFMA kernel)
__global__ __launch_bounds__(256) void k_h(
    const float* __restrict__ x, const float* __restrict__ Wd,
    const float* __restrict__ Aa,
    ushort_t* __restrict__ HbT, float* __restrict__ E1, float* __restrict__ E2)
{
    const int bs = blockIdx.x;
    const int tid = threadIdx.x;
    const int nt = tid >> 3;          // rows nt*8 .. nt*8+7
    const int ot = tid & 7;           // cols ot*8 .. ot*8+7
    __shared__ float Wl[IF * OF];     // 16 KB [k][o]
    __shared__ float a1s[OF], a2s[OF];
    {
        const float4* src = (const float4*)(Wd + (size_t)bs * 4096);
        float4* dst = (float4*)Wl;
        for (int p = 0; p < 4; ++p) dst[tid + p * 256] = src[tid + p * 256];
        if (tid < 64) a1s[tid] = Aa[(size_t)bs * 128 + tid];
        else if (tid < 128) a2s[tid - 64] = Aa[(size_t)bs * 128 + tid];
    }
    __syncthreads();

    const float4* xb = (const float4*)(x + ((size_t)bs * NN + nt * 8) * IF);
    float acc[8][8];
#pragma unroll
    for (int r = 0; r < 8; ++r)
#pragma unroll
        for (int c = 0; c < 8; ++c) acc[r][c] = 0.f;

#pragma unroll
    for (int kq = 0; kq < 16; ++kq) {
        float4 xv[8];
#pragma unroll
        for (int r = 0; r < 8; ++r) xv[r] = xb[r * 16 + kq];
#pragma unroll
        for (int c = 0; c < 4; ++c) {
            const int k = kq * 4 + c;
            const float4 w0 = *(const float4*)&Wl[k * OF + ot * 8];
            const float4 w1 = *(const float4*)&Wl[k * OF + ot * 8 + 4];
#pragma unroll
            for (int r = 0; r < 8; ++r) {
                const float xs = (c == 0) ? xv[r].x : (c == 1) ? xv[r].y
                               : (c == 2) ? xv[r].z : xv[r].w;
                acc[r][0] = fmaf(xs, w0.x, acc[r][0]);
                acc[r][1] = fmaf(xs, w0.y, acc[r][1]);
                acc[r][2] = fmaf(xs, w0.z, acc[r][2]);
                acc[r][3] = fmaf(xs, w0.w, acc[r][3]);
                acc[r][4] = fmaf(xs, w1.x, acc[r][4]);
                acc[r][5] = fmaf(xs, w1.y, acc[r][5]);
                acc[r][6] = fmaf(xs, w1.z, acc[r][6]);
                acc[r][7] = fmaf(xs, w1.w, acc[r][7]);
            }
        }
    }

    const float4 av0 = *(const float4*)&a1s[ot * 8];
    const float4 av1 = *(const float4*)&a1s[ot * 8 + 4];
    const float4 bv0 = *(const float4*)&a2s[ot * 8];
    const float4 bv1 = *(const float4*)&a2s[ot * 8 + 4];
    float e1sel = 0.f, e2sel = 0.f;
#pragma unroll
    for (int r = 0; r < 8; ++r) {
        float p1 = acc[r][0]*av0.x + acc[r][1]*av0.y + acc[r][2]*av0.z + acc[r][3]*av0.w
                 + acc[r][4]*av1.x + acc[r][5]*av1.y + acc[r][6]*av1.z + acc[r][7]*av1.w;
        float p2 = acc[r][0]*bv0.x + acc[r][1]*bv0.y + acc[r][2]*bv0.z + acc[r][3]*bv0.w
                 + acc[r][4]*bv1.x + acc[r][5]*bv1.y + acc[r][6]*bv1.z + acc[r][7]*bv1.w;
        p1 += __shfl_xor(p1, 1, 64); p2 += __shfl_xor(p2, 1, 64);
        p1 += __shfl_xor(p1, 2, 64); p2 += __shfl_xor(p2, 2, 64);
        p1 += __shfl_xor(p1, 4, 64); p2 += __shfl_xor(p2, 4, 64);
        if (ot == r) { e1sel = p1; e2sel = p2; }
    }
    E1[(size_t)bs * NN + tid] = e1sel;
    E2[(size_t)bs * NN + tid] = e2sel;

    ushort_t* hb = HbT + (size_t)bs * (OF * NN);
#pragma unroll
    for (int c = 0; c < 8; ++c) {
        short8 pk;
#pragma unroll
        for (int r = 0; r < 8; ++r) pk[r] = (short)f2bf(acc[r][c]);
        *(short8*)(hb + (size_t)(ot * 8 + c) * NN + nt * 8) = pk;
    }
}

// ------ Kernel 3a: softmax-over-s stats per (b,i,j) stored [b][j][i] ---------
// RT sign encodes the adjacency mask: RT < 0  =>  masked, attn == -RT == 1/64.
__global__ __launch_bounds__(256) void k_softstats(
    const float* __restrict__ E1, const float* __restrict__ E2,
    const float* __restrict__ maskT,
    float* __restrict__ MT, float* __restrict__ RT)
{
    const int bid = blockIdx.x;        // b*256 + j
    const int b = bid >> 8, j = bid & 255;
    const int t = threadIdx.x;         // i
    __shared__ float e1t[SS][NN];
    __shared__ float e2c[SS];
    for (int s = 0; s < SS; ++s)
        e1t[s][t] = E1[(size_t)((b * SS + s) * NN) + t];
    if (t < SS) e2c[t] = E2[(size_t)((b * SS + t) * NN) + j];
    __syncthreads();

    float mx = -3.0e38f;
#pragma unroll
    for (int s = 0; s < SS; ++s) {
        float v = e1t[s][t] + e2c[s];
        v = (v >= 0.f) ? v : ALPHA * v;
        mx = fmaxf(mx, v);
    }
    float sum = 0.f;
#pragma unroll
    for (int s = 0; s < SS; ++s) {
        float v = e1t[s][t] + e2c[s];
        v = (v >= 0.f) ? v : ALPHA * v;
        sum += __expf(v - mx);
    }
    const float mk = maskT[j * NN + t];
    MT[(size_t)bid * NN + t] = mx;
    RT[(size_t)bid * NN + t] = (mk > 0.f) ? (1.f / sum) : -0.015625f;
}

// ------ Kernel 3b: per (b,s): O = ELU(A(256x256) @ H(256x64)) via bf16 MFMA --
__global__ __launch_bounds__(256) void k_attn(
    const ushort_t* __restrict__ HbT, const float* __restrict__ E1,
    const float* __restrict__ E2, const float* __restrict__ MT,
    const float* __restrict__ RT, float* __restrict__ out)
{
    const int bs = blockIdx.x;        // b*64 + s
    const int b = bs >> 6;
    const int tid = threadIdx.x;
    const int wid = tid >> 6;
    const int lane = tid & 63;

    __shared__ ushort_t HT[OF * NN];  // 32 KB  B^T [o][j], XOR-swizzled
    __shared__ ushort_t Als[NN * 64]; // 32 KB  A-chunk [i][jj], XOR-swizzled
    __shared__ float e2s[NN];

    {
        const short8* src = (const short8*)(HbT + (size_t)bs * (OF * NN));
        char* dst = (char*)HT;
#pragma unroll
        for (int p = 0; p < 8; ++p) {
            const int idx = tid + p * 256;
            const int byte = idx * 16;
            const int o = byte >> 9;
            *(short8*)(dst + (byte ^ ((o & 7) << 4))) = src[idx];
        }
    }
    e2s[tid] = E2[(size_t)bs * NN + tid];
    const float ei = E1[(size_t)bs * NN + tid];
    __syncthreads();

    f32x4 acc[4][4];
#pragma unroll
    for (int mt = 0; mt < 4; ++mt)
#pragma unroll
        for (int nt = 0; nt < 4; ++nt) acc[mt][nt] = (f32x4){0.f, 0.f, 0.f, 0.f};

    const char* Ab = (const char*)Als;
    const char* Hb = (const char*)HT;
    const size_t mrbase = ((size_t)b * NN) * NN + tid;

    for (int ch = 0; ch < 4; ++ch) {
        char* Aw = (char*)Als;
#pragma unroll
        for (int g = 0; g < 8; ++g) {
            float mv[8], rv[8];
#pragma unroll
            for (int q = 0; q < 8; ++q) {
                const size_t mo = mrbase + (size_t)(ch * 64 + g * 8 + q) * NN;
                mv[q] = MT[mo];
                rv[q] = RT[mo];
            }
            short8 pk;
#pragma unroll
            for (int q = 0; q < 8; ++q) {
                float v = ei + e2s[ch * 64 + g * 8 + q];
                v = (v >= 0.f) ? v : ALPHA * v;
                const float a = (rv[q] < 0.f) ? -rv[q] : __expf(v - mv[q]) * rv[q];
                pk[q] = (short)f2bf(a);
            }
            const int byte = tid * 128 + g * 16;
            *(short8*)(Aw + (byte ^ ((tid & 7) << 4))) = pk;
        }
        __syncthreads();

        short8 af[4][2], bf[4][2];
#pragma unroll
        for (int mt = 0; mt < 4; ++mt) {
            const int row = wid * 64 + mt * 16 + (lane & 15);
#pragma unroll
            for (int ks = 0; ks < 2; ++ks) {
                const int byte = row * 128 + (ks * 32 + ((lane >> 4) * 8)) * 2;
                af[mt][ks] = *(const short8*)(Ab + (byte ^ ((row & 7) << 4)));
            }
        }
#pragma unroll
        for (int nt = 0; nt < 4; ++nt) {
            const int o = nt * 16 + (lane & 15);
#pragma unroll
            for (int ks = 0; ks < 2; ++ks) {
                const int byte = o * 512 + (ch * 64 + ks * 32 + ((lane >> 4) * 8)) * 2;
                bf[nt][ks] = *(const short8*)(Hb + (byte ^ ((o & 7) << 4)));
            }
        }
#pragma unroll
        for (int mt = 0; mt < 4; ++mt)
#pragma unroll
            for (int nt = 0; nt < 4; ++nt) {
                acc[mt][nt] = __builtin_amdgcn_mfma_f32_16x16x32_bf16(
                    af[mt][0], bf[nt][0], acc[mt][nt], 0, 0, 0);
                acc[mt][nt] = __builtin_amdgcn_mfma_f32_16x16x32_bf16(
                    af[mt][1], bf[nt][1], acc[mt][nt], 0, 0, 0);
            }
        __syncthreads();
    }

    float* ob = out + (size_t)bs * (NN * OF);
#pragma unroll
    for (int mt = 0; mt < 4; ++mt) {
        const int rbase = wid * 64 + mt * 16 + (lane >> 4) * 4;
#pragma unroll
        for (int nt = 0; nt < 4; ++nt) {
            const int o = nt * 16 + (lane & 15);
#pragma unroll
            for (int reg = 0; reg < 4; ++reg) {
                float v = acc[mt][nt][reg];
                v = (v > 0.f) ? v : (__expf(v) - 1.f);
                ob[(size_t)(rbase + reg) * OF + o] = v;
            }
        }
    }
}

extern "C" void kernel_launch(void* const* d_in, const int* in_sizes, int n_in,
                              void* d_out, int out_size, void* d_ws, size_t ws_size,
                              hipStream_t stream)
{
    const float* hyper = (const float*)d_in[0];
    const float* x     = (const float*)d_in[1];
    const int*   Adj   = (const int*)d_in[2];
    const float* w1    = (const float*)d_in[3];
    const float* b1    = (const float*)d_in[4];
    const float* w2    = (const float*)d_in[5];
    const float* b2    = (const float*)d_in[6];
    const float* aw1   = (const float*)d_in[7];
    const float* ab1   = (const float*)d_in[8];
    const float* aw2   = (const float*)d_in[9];
    const float* ab2   = (const float*)d_in[10];
    float* out = (float*)d_out;

    float* ws      = (float*)d_ws;
    float* Wd      = ws;                      // 512*4096
    float* Aa      = Wd + 2097152;            // 512*128
    ushort_t* HbT  = (ushort_t*)(Aa + 65536); // 512*64*256 bf16 (4194304 f-equiv)
    float* E1      = (float*)(HbT + 8388608); // 512*256
    float* E2      = E1 + 131072;             // 512*256
    float* MT      = E2 + 131072;             // 8*256*256
    float* RT      = MT + 524288;             // 8*256*256
    float* maskT   = RT + 524288;             // 256*256
    float* Hdn     = maskT + 65536;           // 512*32

    k_mlp1<<<dim3(128), dim3(256), 0, stream>>>(hyper, w1, b1, aw1, ab1,
                                                aw2, ab2, Hdn, Aa);
    k_w2<<<dim3(512), dim3(256), 0, stream>>>(Hdn, w2, b2, Wd);
    k_maskT<<<dim3(256), dim3(256), 0, stream>>>(Adj, maskT);
    k_h<<<dim3(512), dim3(256), 0, stream>>>(x, Wd, Aa, HbT, E1, E2);
    k_softstats<<<dim3(2048), dim3(256), 0, stream>>>(E1, E2, maskT, MT, RT);
    k_attn<<<dim3(512), dim3(256), 0, stream>>>(HbT, E1, E2, MT, RT, out);
}

// Round 6
// 104.570 us; speedup vs baseline: 3.0571x; 1.0567x over previous
//
#include <hip/hip_runtime.h>
#include <hip/hip_bf16.h>
#include <math.h>

#define BB 8
#define SS 64
#define NN 256
#define ST 128
#define IF 64
#define OF 64
#define H1 32
#define ALPHA 0.2f

typedef short short8 __attribute__((ext_vector_type(8)));
typedef float f32x4 __attribute__((ext_vector_type(4)));
typedef unsigned short ushort_t;

static __device__ __forceinline__ ushort_t f2bf(float f) {
    __hip_bfloat16 h = __float2bfloat16(f);
    return *reinterpret_cast<ushort_t*>(&h);
}

// ---- Kernel 1a: stage-1 MLPs -> Hdn (512x32, ws) and Aa (512x128) ----------
__global__ __launch_bounds__(256) void k_mlp1(
    const float* __restrict__ hyper,
    const float* __restrict__ w1, const float* __restrict__ b1,
    const float* __restrict__ aw1, const float* __restrict__ ab1,
    const float* __restrict__ aw2, const float* __restrict__ ab2,
    float* __restrict__ Hdn, float* __restrict__ Aa)
{
    const int t = threadIdx.x;
    const int bs0 = blockIdx.x * 4;
    __shared__ float hy[4][ST];
    __shared__ float hda_s[4][H1];
    for (int idx = t; idx < 4 * ST; idx += 256)
        hy[idx >> 7][idx & 127] = hyper[(size_t)bs0 * ST + idx];
    __syncthreads();
    if (t < 128) {
        const int q = t >> 5, c = t & 31;
        float acc = b1[c];
#pragma unroll 4
        for (int k = 0; k < ST; ++k) acc = fmaf(hy[q][k], w1[k * H1 + c], acc);
        Hdn[(size_t)(bs0 + q) * H1 + c] = fmaxf(acc, 0.f);
    } else {
        const int tt = t - 128;
        const int q = tt >> 5, c = tt & 31;
        float acc = ab1[c];
#pragma unroll 4
        for (int k = 0; k < ST; ++k) acc = fmaf(hy[q][k], aw1[k * H1 + c], acc);
        hda_s[q][c] = fmaxf(acc, 0.f);
    }
    __syncthreads();
#pragma unroll
    for (int p = 0; p < 2; ++p) {
        const int idx = t + p * 256;
        const int qq = idx >> 7, cc = idx & 127;
        float a = ab2[cc];
#pragma unroll
        for (int k = 0; k < H1; ++k)
            a = fmaf(hda_s[qq][k], aw2[k * 128 + cc], a);
        Aa[(size_t)(bs0 + qq) * 128 + cc] = fabsf(a);
    }
}

// ---- Kernel 1b: W = abs(Hdn(512x32) @ w2(32x4096) + b2) -> Wd --------------
__global__ __launch_bounds__(256) void k_w2(
    const float* __restrict__ Hdn, const float* __restrict__ w2,
    const float* __restrict__ b2, float* __restrict__ Wd)
{
    const int t = threadIdx.x;
    const int bs0 = (blockIdx.x >> 2) * 4;
    const int e0 = (blockIdx.x & 3) * 1024;
    __shared__ float hd[4][H1];
    if (t < 128) hd[t >> 5][t & 31] = Hdn[(size_t)bs0 * H1 + t];
    __syncthreads();

    const int e = e0 + t * 4;
    const float4 bb = *(const float4*)&b2[e];
    float4 a0 = bb, a1 = bb, a2 = bb, a3 = bb;
#pragma unroll
    for (int kq = 0; kq < 8; ++kq) {
        const float4 h0 = *(const float4*)&hd[0][kq * 4];
        const float4 h1 = *(const float4*)&hd[1][kq * 4];
        const float4 h2 = *(const float4*)&hd[2][kq * 4];
        const float4 h3 = *(const float4*)&hd[3][kq * 4];
#pragma unroll
        for (int c = 0; c < 4; ++c) {
            const float4 wv = *(const float4*)&w2[(size_t)(kq * 4 + c) * 4096 + e];
            const float s0 = (c == 0) ? h0.x : (c == 1) ? h0.y : (c == 2) ? h0.z : h0.w;
            const float s1 = (c == 0) ? h1.x : (c == 1) ? h1.y : (c == 2) ? h1.z : h1.w;
            const float s2 = (c == 0) ? h2.x : (c == 1) ? h2.y : (c == 2) ? h2.z : h2.w;
            const float s3 = (c == 0) ? h3.x : (c == 1) ? h3.y : (c == 2) ? h3.z : h3.w;
            a0.x = fmaf(s0, wv.x, a0.x); a0.y = fmaf(s0, wv.y, a0.y);
            a0.z = fmaf(s0, wv.z, a0.z); a0.w = fmaf(s0, wv.w, a0.w);
            a1.x = fmaf(s1, wv.x, a1.x); a1.y = fmaf(s1, wv.y, a1.y);
            a1.z = fmaf(s1, wv.z, a1.z); a1.w = fmaf(s1, wv.w, a1.w);
            a2.x = fmaf(s2, wv.x, a2.x); a2.y = fmaf(s2, wv.y, a2.y);
            a2.z = fmaf(s2, wv.z, a2.z); a2.w = fmaf(s2, wv.w, a2.w);
            a3.x = fmaf(s3, wv.x, a3.x); a3.y = fmaf(s3, wv.y, a3.y);
            a3.z = fmaf(s3, wv.z, a3.z); a3.w = fmaf(s3, wv.w, a3.w);
        }
    }
    a0.x = fabsf(a0.x); a0.y = fabsf(a0.y); a0.z = fabsf(a0.z); a0.w = fabsf(a0.w);
    a1.x = fabsf(a1.x); a1.y = fabsf(a1.y); a1.z = fabsf(a1.z); a1.w = fabsf(a1.w);
    a2.x = fabsf(a2.x); a2.y = fabsf(a2.y); a2.z = fabsf(a2.z); a2.w = fabsf(a2.w);
    a3.x = fabsf(a3.x); a3.y = fabsf(a3.y); a3.z = fabsf(a3.z); a3.w = fabsf(a3.w);
    *(float4*)&Wd[(size_t)(bs0 + 0) * 4096 + e] = a0;
    *(float4*)&Wd[(size_t)(bs0 + 1) * 4096 + e] = a1;
    *(float4*)&Wd[(size_t)(bs0 + 2) * 4096 + e] = a2;
    *(float4*)&Wd[(size_t)(bs0 + 3) * 4096 + e] = a3;
}

// ------------- transpose Adj to float mask [j][i] ----------------------------
__global__ void k_maskT(const int* __restrict__ Adj, float* __restrict__ maskT)
{
    const int i = blockIdx.x, j = threadIdx.x;
    maskT[j * NN + i] = (Adj[i * NN + j] > 0) ? 1.f : 0.f;
}

// ------- Kernel 2: per (b,s): h = x(256x64)@W(64x64) 8x8 reg tiles -----------
// Writes h as bf16 TRANSPOSED: HbT[bs][o][n]  (B^T layout for the MFMA kernel)
__global__ __launch_bounds__(256) void k_h(
    const float* __restrict__ x, const float* __restrict__ Wd,
    const float* __restrict__ Aa,
    ushort_t* __restrict__ HbT, float* __restrict__ E1, float* __restrict__ E2)
{
    const int bs = blockIdx.x;
    const int tid = threadIdx.x;
    const int nt = tid >> 3;
    const int ot = tid & 7;
    __shared__ float Wl[IF * OF];
    __shared__ float a1s[OF], a2s[OF];
    {
        const float4* src = (const float4*)(Wd + (size_t)bs * 4096);
        float4* dst = (float4*)Wl;
        for (int p = 0; p < 4; ++p) dst[tid + p * 256] = src[tid + p * 256];
        if (tid < 64) a1s[tid] = Aa[(size_t)bs * 128 + tid];
        else if (tid < 128) a2s[tid - 64] = Aa[(size_t)bs * 128 + tid];
    }
    __syncthreads();

    const float4* xb = (const float4*)(x + ((size_t)bs * NN + nt * 8) * IF);
    float acc[8][8];
#pragma unroll
    for (int r = 0; r < 8; ++r)
#pragma unroll
        for (int c = 0; c < 8; ++c) acc[r][c] = 0.f;

#pragma unroll
    for (int kq = 0; kq < 16; ++kq) {
        float4 xv[8];
#pragma unroll
        for (int r = 0; r < 8; ++r) xv[r] = xb[r * 16 + kq];
#pragma unroll
        for (int c = 0; c < 4; ++c) {
            const int k = kq * 4 + c;
            const float4 w0 = *(const float4*)&Wl[k * OF + ot * 8];
            const float4 w1 = *(const float4*)&Wl[k * OF + ot * 8 + 4];
#pragma unroll
            for (int r = 0; r < 8; ++r) {
                const float xs = (c == 0) ? xv[r].x : (c == 1) ? xv[r].y
                               : (c == 2) ? xv[r].z : xv[r].w;
                acc[r][0] = fmaf(xs, w0.x, acc[r][0]);
                acc[r][1] = fmaf(xs, w0.y, acc[r][1]);
                acc[r][2] = fmaf(xs, w0.z, acc[r][2]);
                acc[r][3] = fmaf(xs, w0.w, acc[r][3]);
                acc[r][4] = fmaf(xs, w1.x, acc[r][4]);
                acc[r][5] = fmaf(xs, w1.y, acc[r][5]);
                acc[r][6] = fmaf(xs, w1.z, acc[r][6]);
                acc[r][7] = fmaf(xs, w1.w, acc[r][7]);
            }
        }
    }

    const float4 av0 = *(const float4*)&a1s[ot * 8];
    const float4 av1 = *(const float4*)&a1s[ot * 8 + 4];
    const float4 bv0 = *(const float4*)&a2s[ot * 8];
    const float4 bv1 = *(const float4*)&a2s[ot * 8 + 4];
    float e1sel = 0.f, e2sel = 0.f;
#pragma unroll
    for (int r = 0; r < 8; ++r) {
        float p1 = acc[r][0]*av0.x + acc[r][1]*av0.y + acc[r][2]*av0.z + acc[r][3]*av0.w
                 + acc[r][4]*av1.x + acc[r][5]*av1.y + acc[r][6]*av1.z + acc[r][7]*av1.w;
        float p2 = acc[r][0]*bv0.x + acc[r][1]*bv0.y + acc[r][2]*bv0.z + acc[r][3]*bv0.w
                 + acc[r][4]*bv1.x + acc[r][5]*bv1.y + acc[r][6]*bv1.z + acc[r][7]*bv1.w;
        p1 += __shfl_xor(p1, 1, 64); p2 += __shfl_xor(p2, 1, 64);
        p1 += __shfl_xor(p1, 2, 64); p2 += __shfl_xor(p2, 2, 64);
        p1 += __shfl_xor(p1, 4, 64); p2 += __shfl_xor(p2, 4, 64);
        if (ot == r) { e1sel = p1; e2sel = p2; }
    }
    E1[(size_t)bs * NN + tid] = e1sel;
    E2[(size_t)bs * NN + tid] = e2sel;

    ushort_t* hb = HbT + (size_t)bs * (OF * NN);
#pragma unroll
    for (int c = 0; c < 8; ++c) {
        short8 pk;
#pragma unroll
        for (int r = 0; r < 8; ++r) pk[r] = (short)f2bf(acc[r][c]);
        *(short8*)(hb + (size_t)(ot * 8 + c) * NN + nt * 8) = pk;
    }
}

// ------ Kernel 3a: softmax-over-s stats per (b,i,j) stored [b][j][i] ---------
// Block = (b, group of 4 j). 512 blocks: 4x less e1 re-staging than per-j blocks.
// RT sign encodes the adjacency mask: RT < 0  =>  masked, attn == -RT == 1/64.
__global__ __launch_bounds__(256) void k_softstats(
    const float* __restrict__ E1, const float* __restrict__ E2,
    const float* __restrict__ maskT,
    float* __restrict__ MT, float* __restrict__ RT)
{
    const int bid = blockIdx.x;        // b*64 + jg
    const int b = bid >> 6, j0 = (bid & 63) * 4;
    const int t = threadIdx.x;         // i
    __shared__ float e1t[SS][NN];      // 64 KB
    __shared__ float e2c[4][SS];       // 1 KB
    for (int s = 0; s < SS; ++s)
        e1t[s][t] = E1[(size_t)((b * SS + s) * NN) + t];
    {
        const int jj = t >> 6, s = t & 63;
        e2c[jj][s] = E2[(size_t)((b * SS + s) * NN) + j0 + jj];
    }
    __syncthreads();

#pragma unroll
    for (int jj = 0; jj < 4; ++jj) {
        float mx = -3.0e38f;
#pragma unroll
        for (int s = 0; s < SS; ++s) {
            float v = e1t[s][t] + e2c[jj][s];
            v = (v >= 0.f) ? v : ALPHA * v;
            mx = fmaxf(mx, v);
        }
        float sum = 0.f;
#pragma unroll
        for (int s = 0; s < SS; ++s) {
            float v = e1t[s][t] + e2c[jj][s];
            v = (v >= 0.f) ? v : ALPHA * v;
            sum += __expf(v - mx);
        }
        const float mk = maskT[(j0 + jj) * NN + t];
        MT[(size_t)(b * NN + j0 + jj) * NN + t] = mx;
        RT[(size_t)(b * NN + j0 + jj) * NN + t] = (mk > 0.f) ? (1.f / sum) : -0.015625f;
    }
}

// ------ Kernel 3b: per (b,s): O = ELU(A(256x256) @ H(256x64)) via bf16 MFMA --
// Fragment-direct: each lane computes its OWN A-fragment elements in registers
// (exp/leaky from e1s/e2s + MT/RT loads) and loads its B-fragments straight
// from HbT (L2-resident). No matrix LDS, no barriers in the main loop.
__global__ __launch_bounds__(256) void k_attn(
    const ushort_t* __restrict__ HbT, const float* __restrict__ E1,
    const float* __restrict__ E2, const float* __restrict__ MT,
    const float* __restrict__ RT, float* __restrict__ out)
{
    const int bs = blockIdx.x;        // b*64 + s
    const int b = bs >> 6;
    const int tid = threadIdx.x;
    const int wid = tid >> 6;         // wave -> output rows wid*64..+63
    const int lane = tid & 63;
    const int l15 = lane & 15;
    const int lhi = lane >> 4;        // 0..3

    __shared__ float e1s[NN], e2s[NN];   // 2 KB total
    e1s[tid] = E1[(size_t)bs * NN + tid];
    e2s[tid] = E2[(size_t)bs * NN + tid];
    __syncthreads();

    float e1r[4];
#pragma unroll
    for (int mt = 0; mt < 4; ++mt)
        e1r[mt] = e1s[wid * 64 + mt * 16 + l15];

    f32x4 acc[4][4];
#pragma unroll
    for (int mt = 0; mt < 4; ++mt)
#pragma unroll
        for (int nt = 0; nt < 4; ++nt) acc[mt][nt] = (f32x4){0.f, 0.f, 0.f, 0.f};

    const ushort_t* hb = HbT + (size_t)bs * (OF * NN);
    const float* mtb = MT + ((size_t)b * NN) * NN;
    const float* rtb = RT + ((size_t)b * NN) * NN;

    for (int ch = 0; ch < 4; ++ch) {
        // ---- B fragments for this chunk (global, L2-resident, 16B/lane)
        short8 bf[4][2];
#pragma unroll
        for (int nt = 0; nt < 4; ++nt) {
            const int o = nt * 16 + l15;
#pragma unroll
            for (int ks = 0; ks < 2; ++ks) {
                const int j0 = ch * 64 + ks * 32 + lhi * 8;
                bf[nt][ks] = *(const short8*)(hb + (size_t)o * NN + j0);
            }
        }
        // ---- A fragments: computed in-register per mt, then 8 MFMAs
#pragma unroll
        for (int mt = 0; mt < 4; ++mt) {
            const int row = wid * 64 + mt * 16 + l15;
            const float e1v = e1r[mt];
            short8 af[2];
#pragma unroll
            for (int ks = 0; ks < 2; ++ks) {
                const int k0 = ch * 64 + ks * 32 + lhi * 8;
                float mv[8], rv[8];
#pragma unroll
                for (int kk = 0; kk < 8; ++kk) {
                    mv[kk] = mtb[(size_t)(k0 + kk) * NN + row];
                    rv[kk] = rtb[(size_t)(k0 + kk) * NN + row];
                }
                short8 pk;
#pragma unroll
                for (int kk = 0; kk < 8; ++kk) {
                    float v = e1v + e2s[k0 + kk];
                    v = (v >= 0.f) ? v : ALPHA * v;
                    const float a = (rv[kk] < 0.f) ? -rv[kk]
                                                   : __expf(v - mv[kk]) * rv[kk];
                    pk[kk] = (short)f2bf(a);
                }
                af[ks] = pk;
            }
#pragma unroll
            for (int nt = 0; nt < 4; ++nt) {
                acc[mt][nt] = __builtin_amdgcn_mfma_f32_16x16x32_bf16(
                    af[0], bf[nt][0], acc[mt][nt], 0, 0, 0);
                acc[mt][nt] = __builtin_amdgcn_mfma_f32_16x16x32_bf16(
                    af[1], bf[nt][1], acc[mt][nt], 0, 0, 0);
            }
        }
    }

    // ---- epilogue: ELU + store f32
    float* ob = out + (size_t)bs * (NN * OF);
#pragma unroll
    for (int mt = 0; mt < 4; ++mt) {
        const int rbase = wid * 64 + mt * 16 + (lane >> 4) * 4;
#pragma unroll
        for (int nt = 0; nt < 4; ++nt) {
            const int o = nt * 16 + l15;
#pragma unroll
            for (int reg = 0; reg < 4; ++reg) {
                float v = acc[mt][nt][reg];
                v = (v > 0.f) ? v : (__expf(v) - 1.f);
                ob[(size_t)(rbase + reg) * OF + o] = v;
            }
        }
    }
}

extern "C" void kernel_launch(void* const* d_in, const int* in_sizes, int n_in,
                              void* d_out, int out_size, void* d_ws, size_t ws_size,
                              hipStream_t stream)
{
    const float* hyper = (const float*)d_in[0];
    const float* x     = (const float*)d_in[1];
    const int*   Adj   = (const int*)d_in[2];
    const float* w1    = (const float*)d_in[3];
    const float* b1    = (const float*)d_in[4];
    const float* w2    = (const float*)d_in[5];
    const float* b2    = (const float*)d_in[6];
    const float* aw1   = (const float*)d_in[7];
    const float* ab1   = (const float*)d_in[8];
    const float* aw2   = (const float*)d_in[9];
    const float* ab2   = (const float*)d_in[10];
    float* out = (float*)d_out;

    float* ws      = (float*)d_ws;
    float* Wd      = ws;                      // 512*4096
    float* Aa      = Wd + 2097152;            // 512*128
    ushort_t* HbT  = (ushort_t*)(Aa + 65536); // 512*64*256 bf16 (4194304 f-equiv)
    float* E1      = (float*)(HbT + 8388608); // 512*256
    float* E2      = E1 + 131072;             // 512*256
    float* MT      = E2 + 131072;             // 8*256*256
    float* RT      = MT + 524288;             // 8*256*256
    float* maskT   = RT + 524288;             // 256*256
    float* Hdn     = maskT + 65536;           // 512*32

    k_mlp1<<<dim3(128), dim3(256), 0, stream>>>(hyper, w1, b1, aw1, ab1,
                                                aw2, ab2, Hdn, Aa);
    k_w2<<<dim3(512), dim3(256), 0, stream>>>(Hdn, w2, b2, Wd);
    k_maskT<<<dim3(256), dim3(256), 0, stream>>>(Adj, maskT);
    k_h<<<dim3(512), dim3(256), 0, stream>>>(x, Wd, Aa, HbT, E1, E2);
    k_softstats<<<dim3(512), dim3(256), 0, stream>>>(E1, E2, maskT, MT, RT);
    k_attn<<<dim3(512), dim3(256), 0, stream>>>(HbT, E1, E2, MT, RT, out);
}

// Round 7
// 92.793 us; speedup vs baseline: 3.4451x; 1.1269x over previous
//
#include <hip/hip_runtime.h>
#include <hip/hip_bf16.h>
#include <math.h>

#define BB 8
#define SS 64
#define NN 256
#define ST 128
#define IF 64
#define OF 64
#define H1 32
#define ALPHA 0.2f

typedef short short8 __attribute__((ext_vector_type(8)));
typedef float f32x4 __attribute__((ext_vector_type(4)));
typedef unsigned short ushort_t;

static __device__ __forceinline__ ushort_t f2bf(float f) {
    __hip_bfloat16 h = __float2bfloat16(f);
    return *reinterpret_cast<ushort_t*>(&h);
}

// ---- Kernel 1a: stage-1 MLPs -> Hdn (512x32, ws) and Aa (512x128) ----------
__global__ __launch_bounds__(256) void k_mlp1(
    const float* __restrict__ hyper,
    const float* __restrict__ w1, const float* __restrict__ b1,
    const float* __restrict__ aw1, const float* __restrict__ ab1,
    const float* __restrict__ aw2, const float* __restrict__ ab2,
    float* __restrict__ Hdn, float* __restrict__ Aa)
{
    const int t = threadIdx.x;
    const int bs0 = blockIdx.x * 4;
    __shared__ float hy[4][ST];
    __shared__ float hda_s[4][H1];
    for (int idx = t; idx < 4 * ST; idx += 256)
        hy[idx >> 7][idx & 127] = hyper[(size_t)bs0 * ST + idx];
    __syncthreads();
    if (t < 128) {
        const int q = t >> 5, c = t & 31;
        float acc = b1[c];
#pragma unroll 4
        for (int k = 0; k < ST; ++k) acc = fmaf(hy[q][k], w1[k * H1 + c], acc);
        Hdn[(size_t)(bs0 + q) * H1 + c] = fmaxf(acc, 0.f);
    } else {
        const int tt = t - 128;
        const int q = tt >> 5, c = tt & 31;
        float acc = ab1[c];
#pragma unroll 4
        for (int k = 0; k < ST; ++k) acc = fmaf(hy[q][k], aw1[k * H1 + c], acc);
        hda_s[q][c] = fmaxf(acc, 0.f);
    }
    __syncthreads();
#pragma unroll
    for (int p = 0; p < 2; ++p) {
        const int idx = t + p * 256;
        const int qq = idx >> 7, cc = idx & 127;
        float a = ab2[cc];
#pragma unroll
        for (int k = 0; k < H1; ++k)
            a = fmaf(hda_s[qq][k], aw2[k * 128 + cc], a);
        Aa[(size_t)(bs0 + qq) * 128 + cc] = fabsf(a);
    }
}

// ---- Kernel 1b: W = abs(Hdn(512x32) @ w2(32x4096) + b2) -> Wd --------------
__global__ __launch_bounds__(256) void k_w2(
    const float* __restrict__ Hdn, const float* __restrict__ w2,
    const float* __restrict__ b2, float* __restrict__ Wd)
{
    const int t = threadIdx.x;
    const int bs0 = (blockIdx.x >> 2) * 4;
    const int e0 = (blockIdx.x & 3) * 1024;
    __shared__ float hd[4][H1];
    if (t < 128) hd[t >> 5][t & 31] = Hdn[(size_t)bs0 * H1 + t];
    __syncthreads();

    const int e = e0 + t * 4;
    const float4 bb = *(const float4*)&b2[e];
    float4 a0 = bb, a1 = bb, a2 = bb, a3 = bb;
#pragma unroll
    for (int kq = 0; kq < 8; ++kq) {
        const float4 h0 = *(const float4*)&hd[0][kq * 4];
        const float4 h1 = *(const float4*)&hd[1][kq * 4];
        const float4 h2 = *(const float4*)&hd[2][kq * 4];
        const float4 h3 = *(const float4*)&hd[3][kq * 4];
#pragma unroll
        for (int c = 0; c < 4; ++c) {
            const float4 wv = *(const float4*)&w2[(size_t)(kq * 4 + c) * 4096 + e];
            const float s0 = (c == 0) ? h0.x : (c == 1) ? h0.y : (c == 2) ? h0.z : h0.w;
            const float s1 = (c == 0) ? h1.x : (c == 1) ? h1.y : (c == 2) ? h1.z : h1.w;
            const float s2 = (c == 0) ? h2.x : (c == 1) ? h2.y : (c == 2) ? h2.z : h2.w;
            const float s3 = (c == 0) ? h3.x : (c == 1) ? h3.y : (c == 2) ? h3.z : h3.w;
            a0.x = fmaf(s0, wv.x, a0.x); a0.y = fmaf(s0, wv.y, a0.y);
            a0.z = fmaf(s0, wv.z, a0.z); a0.w = fmaf(s0, wv.w, a0.w);
            a1.x = fmaf(s1, wv.x, a1.x); a1.y = fmaf(s1, wv.y, a1.y);
            a1.z = fmaf(s1, wv.z, a1.z); a1.w = fmaf(s1, wv.w, a1.w);
            a2.x = fmaf(s2, wv.x, a2.x); a2.y = fmaf(s2, wv.y, a2.y);
            a2.z = fmaf(s2, wv.z, a2.z); a2.w = fmaf(s2, wv.w, a2.w);
            a3.x = fmaf(s3, wv.x, a3.x); a3.y = fmaf(s3, wv.y, a3.y);
            a3.z = fmaf(s3, wv.z, a3.z); a3.w = fmaf(s3, wv.w, a3.w);
        }
    }
    a0.x = fabsf(a0.x); a0.y = fabsf(a0.y); a0.z = fabsf(a0.z); a0.w = fabsf(a0.w);
    a1.x = fabsf(a1.x); a1.y = fabsf(a1.y); a1.z = fabsf(a1.z); a1.w = fabsf(a1.w);
    a2.x = fabsf(a2.x); a2.y = fabsf(a2.y); a2.z = fabsf(a2.z); a2.w = fabsf(a2.w);
    a3.x = fabsf(a3.x); a3.y = fabsf(a3.y); a3.z = fabsf(a3.z); a3.w = fabsf(a3.w);
    *(float4*)&Wd[(size_t)(bs0 + 0) * 4096 + e] = a0;
    *(float4*)&Wd[(size_t)(bs0 + 1) * 4096 + e] = a1;
    *(float4*)&Wd[(size_t)(bs0 + 2) * 4096 + e] = a2;
    *(float4*)&Wd[(size_t)(bs0 + 3) * 4096 + e] = a3;
}

// ------- Kernel 2: per (b,s): h = x(256x64)@W(64x64) 8x8 reg tiles -----------
// Writes h as bf16 TRANSPOSED: HbT[bs][o][n]  (B^T layout for the MFMA kernel)
__global__ __launch_bounds__(256) void k_h(
    const float* __restrict__ x, const float* __restrict__ Wd,
    const float* __restrict__ Aa,
    ushort_t* __restrict__ HbT, float* __restrict__ E1, float* __restrict__ E2)
{
    const int bs = blockIdx.x;
    const int tid = threadIdx.x;
    const int nt = tid >> 3;
    const int ot = tid & 7;
    __shared__ float Wl[IF * OF];
    __shared__ float a1s[OF], a2s[OF];
    {
        const float4* src = (const float4*)(Wd + (size_t)bs * 4096);
        float4* dst = (float4*)Wl;
        for (int p = 0; p < 4; ++p) dst[tid + p * 256] = src[tid + p * 256];
        if (tid < 64) a1s[tid] = Aa[(size_t)bs * 128 + tid];
        else if (tid < 128) a2s[tid - 64] = Aa[(size_t)bs * 128 + tid];
    }
    __syncthreads();

    const float4* xb = (const float4*)(x + ((size_t)bs * NN + nt * 8) * IF);
    float acc[8][8];
#pragma unroll
    for (int r = 0; r < 8; ++r)
#pragma unroll
        for (int c = 0; c < 8; ++c) acc[r][c] = 0.f;

#pragma unroll
    for (int kq = 0; kq < 16; ++kq) {
        float4 xv[8];
#pragma unroll
        for (int r = 0; r < 8; ++r) xv[r] = xb[r * 16 + kq];
#pragma unroll
        for (int c = 0; c < 4; ++c) {
            const int k = kq * 4 + c;
            const float4 w0 = *(const float4*)&Wl[k * OF + ot * 8];
            const float4 w1 = *(const float4*)&Wl[k * OF + ot * 8 + 4];
#pragma unroll
            for (int r = 0; r < 8; ++r) {
                const float xs = (c == 0) ? xv[r].x : (c == 1) ? xv[r].y
                               : (c == 2) ? xv[r].z : xv[r].w;
                acc[r][0] = fmaf(xs, w0.x, acc[r][0]);
                acc[r][1] = fmaf(xs, w0.y, acc[r][1]);
                acc[r][2] = fmaf(xs, w0.z, acc[r][2]);
                acc[r][3] = fmaf(xs, w0.w, acc[r][3]);
                acc[r][4] = fmaf(xs, w1.x, acc[r][4]);
                acc[r][5] = fmaf(xs, w1.y, acc[r][5]);
                acc[r][6] = fmaf(xs, w1.z, acc[r][6]);
                acc[r][7] = fmaf(xs, w1.w, acc[r][7]);
            }
        }
    }

    const float4 av0 = *(const float4*)&a1s[ot * 8];
    const float4 av1 = *(const float4*)&a1s[ot * 8 + 4];
    const float4 bv0 = *(const float4*)&a2s[ot * 8];
    const float4 bv1 = *(const float4*)&a2s[ot * 8 + 4];
    float e1sel = 0.f, e2sel = 0.f;
#pragma unroll
    for (int r = 0; r < 8; ++r) {
        float p1 = acc[r][0]*av0.x + acc[r][1]*av0.y + acc[r][2]*av0.z + acc[r][3]*av0.w
                 + acc[r][4]*av1.x + acc[r][5]*av1.y + acc[r][6]*av1.z + acc[r][7]*av1.w;
        float p2 = acc[r][0]*bv0.x + acc[r][1]*bv0.y + acc[r][2]*bv0.z + acc[r][3]*bv0.w
                 + acc[r][4]*bv1.x + acc[r][5]*bv1.y + acc[r][6]*bv1.z + acc[r][7]*bv1.w;
        p1 += __shfl_xor(p1, 1, 64); p2 += __shfl_xor(p2, 1, 64);
        p1 += __shfl_xor(p1, 2, 64); p2 += __shfl_xor(p2, 2, 64);
        p1 += __shfl_xor(p1, 4, 64); p2 += __shfl_xor(p2, 4, 64);
        if (ot == r) { e1sel = p1; e2sel = p2; }
    }
    E1[(size_t)bs * NN + tid] = e1sel;
    E2[(size_t)bs * NN + tid] = e2sel;

    ushort_t* hb = HbT + (size_t)bs * (OF * NN);
#pragma unroll
    for (int c = 0; c < 8; ++c) {
        short8 pk;
#pragma unroll
        for (int r = 0; r < 8; ++r) pk[r] = (short)f2bf(acc[r][c]);
        *(short8*)(hb + (size_t)(ot * 8 + c) * NN + nt * 8) = pk;
    }
}

// ------ Kernel 3a: softmax-over-s stats, PACKED bf16 (M,R) -> MR[b][i][j] ----
// Lane = j (coalesced). Block = (b, group of 4 i). Reads Adj directly.
// R sign encodes the mask: R < 0  =>  masked, attn == -R == 1/64.
// R is computed against the bf16-rounded M actually stored, so the softmax
// identity is exact; only R's own bf16 rounding (~0.4%) enters.
__global__ __launch_bounds__(256) void k_softstats(
    const float* __restrict__ E1, const float* __restrict__ E2,
    const int* __restrict__ Adj, unsigned int* __restrict__ MR)
{
    const int bid = blockIdx.x;        // b*64 + ig
    const int b = bid >> 6, i0 = (bid & 63) * 4;
    const int t = threadIdx.x;         // j
    __shared__ float e1s[4][SS];       // 1 KB
    {
        const int ii = t >> 6, s = t & 63;
        e1s[ii][s] = E1[(size_t)(b * SS + s) * NN + i0 + ii];
    }
    float e2r[SS];
#pragma unroll
    for (int s = 0; s < SS; ++s)
        e2r[s] = E2[(size_t)(b * SS + s) * NN + t];
    __syncthreads();

#pragma unroll
    for (int ii = 0; ii < 4; ++ii) {
        float mx = -3.0e38f;
#pragma unroll
        for (int s = 0; s < SS; ++s) {
            float v = e1s[ii][s] + e2r[s];
            v = (v >= 0.f) ? v : ALPHA * v;
            mx = fmaxf(mx, v);
        }
        const unsigned int mu = (unsigned int)f2bf(mx);
        const float mUse = __uint_as_float(mu << 16);
        float sum = 0.f;
#pragma unroll
        for (int s = 0; s < SS; ++s) {
            float v = e1s[ii][s] + e2r[s];
            v = (v >= 0.f) ? v : ALPHA * v;
            sum += __expf(v - mUse);
        }
        const int adj = Adj[(size_t)(i0 + ii) * NN + t];
        const float r = (adj > 0) ? (1.f / sum) : -0.015625f;
        MR[(size_t)(b * NN + i0 + ii) * NN + t] =
            (mu << 16) | (unsigned int)f2bf(r);
    }
}

// ------ Kernel 3b: per (b,s): O = ELU(A(256x256) @ H(256x64)) via bf16 MFMA --
// Fragment-direct A-build; stats come from the PACKED MR table:
// per (mt,ks) one 32B run -> 2 dwordx4 loads (was 16 dword loads).
__global__ __launch_bounds__(256) void k_attn(
    const ushort_t* __restrict__ HbT, const float* __restrict__ E1,
    const float* __restrict__ E2, const unsigned int* __restrict__ MR,
    float* __restrict__ out)
{
    const int bs = blockIdx.x;        // b*64 + s
    const int b = bs >> 6;
    const int tid = threadIdx.x;
    const int wid = tid >> 6;         // wave -> output rows wid*64..+63
    const int lane = tid & 63;
    const int l15 = lane & 15;
    const int lhi = lane >> 4;        // 0..3

    __shared__ float e2s[NN];         // 1 KB
    e2s[tid] = E2[(size_t)bs * NN + tid];
    __syncthreads();

    float e1r[4];
#pragma unroll
    for (int mt = 0; mt < 4; ++mt)
        e1r[mt] = E1[(size_t)bs * NN + wid * 64 + mt * 16 + l15];

    f32x4 acc[4][4];
#pragma unroll
    for (int mt = 0; mt < 4; ++mt)
#pragma unroll
        for (int nt = 0; nt < 4; ++nt) acc[mt][nt] = (f32x4){0.f, 0.f, 0.f, 0.f};

    const ushort_t* hb = HbT + (size_t)bs * (OF * NN);
    const unsigned int* mrb = MR + ((size_t)b * NN) * NN;

    for (int ch = 0; ch < 4; ++ch) {
        // ---- B fragments (global, L2-resident, 16B/lane)
        short8 bf[4][2];
#pragma unroll
        for (int nt = 0; nt < 4; ++nt) {
            const int o = nt * 16 + l15;
#pragma unroll
            for (int ks = 0; ks < 2; ++ks) {
                const int j0 = ch * 64 + ks * 32 + lhi * 8;
                bf[nt][ks] = *(const short8*)(hb + (size_t)o * NN + j0);
            }
        }
        // ---- e2 slice for this lane's k-positions (vector LDS reads)
        float e2v[2][8];
#pragma unroll
        for (int ks = 0; ks < 2; ++ks) {
            const int k0 = ch * 64 + ks * 32 + lhi * 8;
            const float4 lo = *(const float4*)&e2s[k0];
            const float4 hi = *(const float4*)&e2s[k0 + 4];
            e2v[ks][0] = lo.x; e2v[ks][1] = lo.y; e2v[ks][2] = lo.z; e2v[ks][3] = lo.w;
            e2v[ks][4] = hi.x; e2v[ks][5] = hi.y; e2v[ks][6] = hi.z; e2v[ks][7] = hi.w;
        }
        // ---- A fragments per mt (packed MR loads), then 8 MFMAs
#pragma unroll
        for (int mt = 0; mt < 4; ++mt) {
            const int row = wid * 64 + mt * 16 + l15;
            const float e1v = e1r[mt];
            const uint4* mrow = (const uint4*)(mrb + (size_t)row * NN);
            short8 af[2];
#pragma unroll
            for (int ks = 0; ks < 2; ++ks) {
                const int k0 = ch * 64 + ks * 32 + lhi * 8;
                const uint4 m0 = mrow[k0 >> 2];
                const uint4 m1 = mrow[(k0 >> 2) + 1];
                const unsigned int wv[8] = {m0.x, m0.y, m0.z, m0.w,
                                            m1.x, m1.y, m1.z, m1.w};
                short8 pk;
#pragma unroll
                for (int kk = 0; kk < 8; ++kk) {
                    const float Mf = __uint_as_float(wv[kk] & 0xFFFF0000u);
                    const float Rf = __uint_as_float(wv[kk] << 16);
                    float v = e1v + e2v[ks][kk];
                    v = (v >= 0.f) ? v : ALPHA * v;
                    const float a = (Rf < 0.f) ? -Rf : __expf(v - Mf) * Rf;
                    pk[kk] = (short)f2bf(a);
                }
                af[ks] = pk;
            }
#pragma unroll
            for (int nt = 0; nt < 4; ++nt) {
                acc[mt][nt] = __builtin_amdgcn_mfma_f32_16x16x32_bf16(
                    af[0], bf[nt][0], acc[mt][nt], 0, 0, 0);
                acc[mt][nt] = __builtin_amdgcn_mfma_f32_16x16x32_bf16(
                    af[1], bf[nt][1], acc[mt][nt], 0, 0, 0);
            }
        }
    }

    // ---- epilogue: ELU + store f32
    float* ob = out + (size_t)bs * (NN * OF);
#pragma unroll
    for (int mt = 0; mt < 4; ++mt) {
        const int rbase = wid * 64 + mt * 16 + (lane >> 4) * 4;
#pragma unroll
        for (int nt = 0; nt < 4; ++nt) {
            const int o = nt * 16 + l15;
#pragma unroll
            for (int reg = 0; reg < 4; ++reg) {
                float v = acc[mt][nt][reg];
                v = (v > 0.f) ? v : (__expf(v) - 1.f);
                ob[(size_t)(rbase + reg) * OF + o] = v;
            }
        }
    }
}

extern "C" void kernel_launch(void* const* d_in, const int* in_sizes, int n_in,
                              void* d_out, int out_size, void* d_ws, size_t ws_size,
                              hipStream_t stream)
{
    const float* hyper = (const float*)d_in[0];
    const float* x     = (const float*)d_in[1];
    const int*   Adj   = (const int*)d_in[2];
    const float* w1    = (const float*)d_in[3];
    const float* b1    = (const float*)d_in[4];
    const float* w2    = (const float*)d_in[5];
    const float* b2    = (const float*)d_in[6];
    const float* aw1   = (const float*)d_in[7];
    const float* ab1   = (const float*)d_in[8];
    const float* aw2   = (const float*)d_in[9];
    const float* ab2   = (const float*)d_in[10];
    float* out = (float*)d_out;

    float* ws      = (float*)d_ws;
    float* Wd      = ws;                      // 512*4096
    float* Aa      = Wd + 2097152;            // 512*128
    ushort_t* HbT  = (ushort_t*)(Aa + 65536); // 512*64*256 bf16 (4194304 f-equiv)
    float* E1      = (float*)(HbT + 8388608); // 512*256
    float* E2      = E1 + 131072;             // 512*256
    unsigned int* MRp = (unsigned int*)(E2 + 131072); // 8*256*256 packed
    float* Hdn     = (float*)(MRp + 524288);  // 512*32

    k_mlp1<<<dim3(128), dim3(256), 0, stream>>>(hyper, w1, b1, aw1, ab1,
                                                aw2, ab2, Hdn, Aa);
    k_w2<<<dim3(512), dim3(256), 0, stream>>>(Hdn, w2, b2, Wd);
    k_h<<<dim3(512), dim3(256), 0, stream>>>(x, Wd, Aa, HbT, E1, E2);
    k_softstats<<<dim3(512), dim3(256), 0, stream>>>(E1, E2, Adj, MRp);
    k_attn<<<dim3(512), dim3(256), 0, stream>>>(HbT, E1, E2, MRp, out);
}

// Round 8
// 90.754 us; speedup vs baseline: 3.5225x; 1.0225x over previous
//
#include <hip/hip_runtime.h>
#include <hip/hip_bf16.h>
#include <math.h>

#define BB 8
#define SS 64
#define NN 256
#define ST 128
#define IF 64
#define OF 64
#define H1 32
#define ALPHA 0.2f

typedef short short8 __attribute__((ext_vector_type(8)));
typedef float f32x4 __attribute__((ext_vector_type(4)));
typedef unsigned short ushort_t;

static __device__ __forceinline__ ushort_t f2bf(float f) {
    __hip_bfloat16 h = __float2bfloat16(f);
    return *reinterpret_cast<ushort_t*>(&h);
}

// ---- Kernel 1 (fused): stage-1 MLPs + Aa + W-gen. Block = 2 bs, 512 thr ----
__global__ __launch_bounds__(512) void k_hyper2(
    const float* __restrict__ hyper,
    const float* __restrict__ w1, const float* __restrict__ b1,
    const float* __restrict__ w2, const float* __restrict__ b2,
    const float* __restrict__ aw1, const float* __restrict__ ab1,
    const float* __restrict__ aw2, const float* __restrict__ ab2,
    float* __restrict__ Wd, float* __restrict__ Aa)
{
    const int t = threadIdx.x;
    const int bs0 = blockIdx.x * 2;
    __shared__ float hy[2][ST];       // 1 KB
    __shared__ float hdn_s[2][H1];    // 256 B
    __shared__ float hda_s[2][H1];    // 256 B
    if (t < 2 * ST)
        hy[t >> 7][t & 127] = hyper[(size_t)bs0 * ST + t];
    __syncthreads();
    if (t < 64) {
        const int q = t >> 5, c = t & 31;
        float acc = b1[c];
#pragma unroll 4
        for (int k = 0; k < ST; ++k) acc = fmaf(hy[q][k], w1[k * H1 + c], acc);
        hdn_s[q][c] = fmaxf(acc, 0.f);
    } else if (t < 128) {
        const int tt = t - 64;
        const int q = tt >> 5, c = tt & 31;
        float acc = ab1[c];
#pragma unroll 4
        for (int k = 0; k < ST; ++k) acc = fmaf(hy[q][k], aw1[k * H1 + c], acc);
        hda_s[q][c] = fmaxf(acc, 0.f);
    }
    __syncthreads();
    // Aa: 2 bs x 128 outputs
    if (t < 256) {
        const int q = t >> 7, c = t & 127;
        float a = ab2[c];
#pragma unroll
        for (int k = 0; k < H1; ++k)
            a = fmaf(hda_s[q][k], aw2[k * 128 + c], a);
        Aa[(size_t)(bs0 + q) * 128 + c] = fabsf(a);
    }
    // W: 2 bs x 4096 e; thread covers e = t*4 + p*2048, p = 0..1
#pragma unroll
    for (int p = 0; p < 2; ++p) {
        const int e = t * 4 + p * 2048;
        const float4 bb = *(const float4*)&b2[e];
        float4 a0 = bb, a1 = bb;
#pragma unroll
        for (int kq = 0; kq < 8; ++kq) {
            const float4 h0 = *(const float4*)&hdn_s[0][kq * 4];
            const float4 h1 = *(const float4*)&hdn_s[1][kq * 4];
#pragma unroll
            for (int c = 0; c < 4; ++c) {
                const float4 wv = *(const float4*)&w2[(size_t)(kq * 4 + c) * 4096 + e];
                const float s0 = (c == 0) ? h0.x : (c == 1) ? h0.y : (c == 2) ? h0.z : h0.w;
                const float s1 = (c == 0) ? h1.x : (c == 1) ? h1.y : (c == 2) ? h1.z : h1.w;
                a0.x = fmaf(s0, wv.x, a0.x); a0.y = fmaf(s0, wv.y, a0.y);
                a0.z = fmaf(s0, wv.z, a0.z); a0.w = fmaf(s0, wv.w, a0.w);
                a1.x = fmaf(s1, wv.x, a1.x); a1.y = fmaf(s1, wv.y, a1.y);
                a1.z = fmaf(s1, wv.z, a1.z); a1.w = fmaf(s1, wv.w, a1.w);
            }
        }
        a0.x = fabsf(a0.x); a0.y = fabsf(a0.y); a0.z = fabsf(a0.z); a0.w = fabsf(a0.w);
        a1.x = fabsf(a1.x); a1.y = fabsf(a1.y); a1.z = fabsf(a1.z); a1.w = fabsf(a1.w);
        *(float4*)&Wd[(size_t)(bs0 + 0) * 4096 + e] = a0;
        *(float4*)&Wd[(size_t)(bs0 + 1) * 4096 + e] = a1;
    }
}

// ------- Kernel 2: per (b,s): h = x(256x64)@W(64x64) 8x8 reg tiles -----------
// Writes h as bf16 TRANSPOSED: HbT[bs][o][n]  (B^T layout for the MFMA kernel)
__global__ __launch_bounds__(256) void k_h(
    const float* __restrict__ x, const float* __restrict__ Wd,
    const float* __restrict__ Aa,
    ushort_t* __restrict__ HbT, float* __restrict__ E1, float* __restrict__ E2)
{
    const int bs = blockIdx.x;
    const int tid = threadIdx.x;
    const int nt = tid >> 3;
    const int ot = tid & 7;
    __shared__ float Wl[IF * OF];
    __shared__ float a1s[OF], a2s[OF];
    {
        const float4* src = (const float4*)(Wd + (size_t)bs * 4096);
        float4* dst = (float4*)Wl;
        for (int p = 0; p < 4; ++p) dst[tid + p * 256] = src[tid + p * 256];
        if (tid < 64) a1s[tid] = Aa[(size_t)bs * 128 + tid];
        else if (tid < 128) a2s[tid - 64] = Aa[(size_t)bs * 128 + tid];
    }
    __syncthreads();

    const float4* xb = (const float4*)(x + ((size_t)bs * NN + nt * 8) * IF);
    float acc[8][8];
#pragma unroll
    for (int r = 0; r < 8; ++r)
#pragma unroll
        for (int c = 0; c < 8; ++c) acc[r][c] = 0.f;

#pragma unroll
    for (int kq = 0; kq < 16; ++kq) {
        float4 xv[8];
#pragma unroll
        for (int r = 0; r < 8; ++r) xv[r] = xb[r * 16 + kq];
#pragma unroll
        for (int c = 0; c < 4; ++c) {
            const int k = kq * 4 + c;
            const float4 w0 = *(const float4*)&Wl[k * OF + ot * 8];
            const float4 w1 = *(const float4*)&Wl[k * OF + ot * 8 + 4];
#pragma unroll
            for (int r = 0; r < 8; ++r) {
                const float xs = (c == 0) ? xv[r].x : (c == 1) ? xv[r].y
                               : (c == 2) ? xv[r].z : xv[r].w;
                acc[r][0] = fmaf(xs, w0.x, acc[r][0]);
                acc[r][1] = fmaf(xs, w0.y, acc[r][1]);
                acc[r][2] = fmaf(xs, w0.z, acc[r][2]);
                acc[r][3] = fmaf(xs, w0.w, acc[r][3]);
                acc[r][4] = fmaf(xs, w1.x, acc[r][4]);
                acc[r][5] = fmaf(xs, w1.y, acc[r][5]);
                acc[r][6] = fmaf(xs, w1.z, acc[r][6]);
                acc[r][7] = fmaf(xs, w1.w, acc[r][7]);
            }
        }
    }

    const float4 av0 = *(const float4*)&a1s[ot * 8];
    const float4 av1 = *(const float4*)&a1s[ot * 8 + 4];
    const float4 bv0 = *(const float4*)&a2s[ot * 8];
    const float4 bv1 = *(const float4*)&a2s[ot * 8 + 4];
    float e1sel = 0.f, e2sel = 0.f;
#pragma unroll
    for (int r = 0; r < 8; ++r) {
        float p1 = acc[r][0]*av0.x + acc[r][1]*av0.y + acc[r][2]*av0.z + acc[r][3]*av0.w
                 + acc[r][4]*av1.x + acc[r][5]*av1.y + acc[r][6]*av1.z + acc[r][7]*av1.w;
        float p2 = acc[r][0]*bv0.x + acc[r][1]*bv0.y + acc[r][2]*bv0.z + acc[r][3]*bv0.w
                 + acc[r][4]*bv1.x + acc[r][5]*bv1.y + acc[r][6]*bv1.z + acc[r][7]*bv1.w;
        p1 += __shfl_xor(p1, 1, 64); p2 += __shfl_xor(p2, 1, 64);
        p1 += __shfl_xor(p1, 2, 64); p2 += __shfl_xor(p2, 2, 64);
        p1 += __shfl_xor(p1, 4, 64); p2 += __shfl_xor(p2, 4, 64);
        if (ot == r) { e1sel = p1; e2sel = p2; }
    }
    E1[(size_t)bs * NN + tid] = e1sel;
    E2[(size_t)bs * NN + tid] = e2sel;

    ushort_t* hb = HbT + (size_t)bs * (OF * NN);
#pragma unroll
    for (int c = 0; c < 8; ++c) {
        short8 pk;
#pragma unroll
        for (int r = 0; r < 8; ++r) pk[r] = (short)f2bf(acc[r][c]);
        *(short8*)(hb + (size_t)(ot * 8 + c) * NN + nt * 8) = pk;
    }
}

// ------ Kernel 3a: softmax-over-s stats, PACKED bf16 (M,R) -> MR[b][i][j] ----
__global__ __launch_bounds__(256) void k_softstats(
    const float* __restrict__ E1, const float* __restrict__ E2,
    const int* __restrict__ Adj, unsigned int* __restrict__ MR)
{
    const int bid = blockIdx.x;        // b*64 + ig
    const int b = bid >> 6, i0 = (bid & 63) * 4;
    const int t = threadIdx.x;         // j
    __shared__ float e1s[4][SS];       // 1 KB
    {
        const int ii = t >> 6, s = t & 63;
        e1s[ii][s] = E1[(size_t)(b * SS + s) * NN + i0 + ii];
    }
    float e2r[SS];
#pragma unroll
    for (int s = 0; s < SS; ++s)
        e2r[s] = E2[(size_t)(b * SS + s) * NN + t];
    __syncthreads();

#pragma unroll
    for (int ii = 0; ii < 4; ++ii) {
        float mx = -3.0e38f;
#pragma unroll
        for (int s = 0; s < SS; ++s) {
            float v = e1s[ii][s] + e2r[s];
            v = (v >= 0.f) ? v : ALPHA * v;
            mx = fmaxf(mx, v);
        }
        const unsigned int mu = (unsigned int)f2bf(mx);
        const float mUse = __uint_as_float(mu << 16);
        float sum = 0.f;
#pragma unroll
        for (int s = 0; s < SS; ++s) {
            float v = e1s[ii][s] + e2r[s];
            v = (v >= 0.f) ? v : ALPHA * v;
            sum += __expf(v - mUse);
        }
        const int adj = Adj[(size_t)(i0 + ii) * NN + t];
        const float r = (adj > 0) ? (1.f / sum) : -0.015625f;
        MR[(size_t)(b * NN + i0 + ii) * NN + t] =
            (mu << 16) | (unsigned int)f2bf(r);
    }
}

// ------ Kernel 3b: per (b,s): O = ELU(A(256x256) @ H(256x64)) via bf16 MFMA --
// 512 threads / 8 waves per block: each wave owns 32 output rows -> 4 waves/SIMD
// of latency cover for the MR/B load streams. Fragment-direct A build.
__global__ __launch_bounds__(512) void k_attn(
    const ushort_t* __restrict__ HbT, const float* __restrict__ E1,
    const float* __restrict__ E2, const unsigned int* __restrict__ MR,
    float* __restrict__ out)
{
    const int bs = blockIdx.x;        // b*64 + s
    const int b = bs >> 6;
    const int tid = threadIdx.x;
    const int wid = tid >> 6;         // wave 0..7 -> output rows wid*32..+31
    const int lane = tid & 63;
    const int l15 = lane & 15;
    const int lhi = lane >> 4;        // 0..3

    __shared__ float e2s[NN];         // 1 KB
    if (tid < NN) e2s[tid] = E2[(size_t)bs * NN + tid];
    __syncthreads();

    float e1r[2];
#pragma unroll
    for (int mt = 0; mt < 2; ++mt)
        e1r[mt] = E1[(size_t)bs * NN + wid * 32 + mt * 16 + l15];

    f32x4 acc[2][4];
#pragma unroll
    for (int mt = 0; mt < 2; ++mt)
#pragma unroll
        for (int nt = 0; nt < 4; ++nt) acc[mt][nt] = (f32x4){0.f, 0.f, 0.f, 0.f};

    const ushort_t* hb = HbT + (size_t)bs * (OF * NN);
    const unsigned int* mrb = MR + ((size_t)b * NN) * NN;

    for (int ch = 0; ch < 4; ++ch) {
        // ---- B fragments (global, L2-resident, 16B/lane)
        short8 bf[4][2];
#pragma unroll
        for (int nt = 0; nt < 4; ++nt) {
            const int o = nt * 16 + l15;
#pragma unroll
            for (int ks = 0; ks < 2; ++ks) {
                const int j0 = ch * 64 + ks * 32 + lhi * 8;
                bf[nt][ks] = *(const short8*)(hb + (size_t)o * NN + j0);
            }
        }
        // ---- e2 slice for this lane's k-positions (vector LDS reads)
        float e2v[2][8];
#pragma unroll
        for (int ks = 0; ks < 2; ++ks) {
            const int k0 = ch * 64 + ks * 32 + lhi * 8;
            const float4 lo = *(const float4*)&e2s[k0];
            const float4 hi = *(const float4*)&e2s[k0 + 4];
            e2v[ks][0] = lo.x; e2v[ks][1] = lo.y; e2v[ks][2] = lo.z; e2v[ks][3] = lo.w;
            e2v[ks][4] = hi.x; e2v[ks][5] = hi.y; e2v[ks][6] = hi.z; e2v[ks][7] = hi.w;
        }
        // ---- A fragments per mt (packed MR loads), then 8 MFMAs
#pragma unroll
        for (int mt = 0; mt < 2; ++mt) {
            const int row = wid * 32 + mt * 16 + l15;
            const float e1v = e1r[mt];
            const uint4* mrow = (const uint4*)(mrb + (size_t)row * NN);
            short8 af[2];
#pragma unroll
            for (int ks = 0; ks < 2; ++ks) {
                const int k0 = ch * 64 + ks * 32 + lhi * 8;
                const uint4 m0 = mrow[k0 >> 2];
                const uint4 m1 = mrow[(k0 >> 2) + 1];
                const unsigned int wv[8] = {m0.x, m0.y, m0.z, m0.w,
                                            m1.x, m1.y, m1.z, m1.w};
                short8 pk;
#pragma unroll
                for (int kk = 0; kk < 8; ++kk) {
                    const float Mf = __uint_as_float(wv[kk] & 0xFFFF0000u);
                    const float Rf = __uint_as_float(wv[kk] << 16);
                    float v = e1v + e2v[ks][kk];
                    v = (v >= 0.f) ? v : ALPHA * v;
                    const float a = (Rf < 0.f) ? -Rf : __expf(v - Mf) * Rf;
                    pk[kk] = (short)f2bf(a);
                }
                af[ks] = pk;
            }
#pragma unroll
            for (int nt = 0; nt < 4; ++nt) {
                acc[mt][nt] = __builtin_amdgcn_mfma_f32_16x16x32_bf16(
                    af[0], bf[nt][0], acc[mt][nt], 0, 0, 0);
                acc[mt][nt] = __builtin_amdgcn_mfma_f32_16x16x32_bf16(
                    af[1], bf[nt][1], acc[mt][nt], 0, 0, 0);
            }
        }
    }

    // ---- epilogue: ELU + store f32
    float* ob = out + (size_t)bs * (NN * OF);
#pragma unroll
    for (int mt = 0; mt < 2; ++mt) {
        const int rbase = wid * 32 + mt * 16 + lhi * 4;
#pragma unroll
        for (int nt = 0; nt < 4; ++nt) {
            const int o = nt * 16 + l15;
#pragma unroll
            for (int reg = 0; reg < 4; ++reg) {
                float v = acc[mt][nt][reg];
                v = (v > 0.f) ? v : (__expf(v) - 1.f);
                ob[(size_t)(rbase + reg) * OF + o] = v;
            }
        }
    }
}

extern "C" void kernel_launch(void* const* d_in, const int* in_sizes, int n_in,
                              void* d_out, int out_size, void* d_ws, size_t ws_size,
                              hipStream_t stream)
{
    const float* hyper = (const float*)d_in[0];
    const float* x     = (const float*)d_in[1];
    const int*   Adj   = (const int*)d_in[2];
    const float* w1    = (const float*)d_in[3];
    const float* b1    = (const float*)d_in[4];
    const float* w2    = (const float*)d_in[5];
    const float* b2    = (const float*)d_in[6];
    const float* aw1   = (const float*)d_in[7];
    const float* ab1   = (const float*)d_in[8];
    const float* aw2   = (const float*)d_in[9];
    const float* ab2   = (const float*)d_in[10];
    float* out = (float*)d_out;

    float* ws      = (float*)d_ws;
    float* Wd      = ws;                      // 512*4096
    float* Aa      = Wd + 2097152;            // 512*128
    ushort_t* HbT  = (ushort_t*)(Aa + 65536); // 512*64*256 bf16 (4194304 f-equiv)
    float* E1      = (float*)(HbT + 8388608); // 512*256
    float* E2      = E1 + 131072;             // 512*256
    unsigned int* MRp = (unsigned int*)(E2 + 131072); // 8*256*256 packed

    k_hyper2<<<dim3(256), dim3(512), 0, stream>>>(hyper, w1, b1, w2, b2,
                                                  aw1, ab1, aw2, ab2, Wd, Aa);
    k_h<<<dim3(512), dim3(256), 0, stream>>>(x, Wd, Aa, HbT, E1, E2);
    k_softstats<<<dim3(512), dim3(256), 0, stream>>>(E1, E2, Adj, MRp);
    k_attn<<<dim3(512), dim3(512), 0, stream>>>(HbT, E1, E2, MRp, out);
}

// Round 9
// 88.202 us; speedup vs baseline: 3.6244x; 1.0289x over previous
//
#include <hip/hip_runtime.h>
#include <hip/hip_bf16.h>
#include <math.h>

#define BB 8
#define SS 64
#define NN 256
#define ST 128
#define IF 64
#define OF 64
#define H1 32
#define ALPHA 0.2f
#define LOG2E 1.4426950408889634f

typedef short short8 __attribute__((ext_vector_type(8)));
typedef short short4_t __attribute__((ext_vector_type(4)));
typedef float f32x4 __attribute__((ext_vector_type(4)));
typedef unsigned short ushort_t;

static __device__ __forceinline__ ushort_t f2bf(float f) {
    __hip_bfloat16 h = __float2bfloat16(f);
    return *reinterpret_cast<ushort_t*>(&h);
}

// ---- Kernel 1 (fused): stage-1 MLPs + Aa + W-gen. Block = 2 bs, 512 thr ----
__global__ __launch_bounds__(512) void k_hyper2(
    const float* __restrict__ hyper,
    const float* __restrict__ w1, const float* __restrict__ b1,
    const float* __restrict__ w2, const float* __restrict__ b2,
    const float* __restrict__ aw1, const float* __restrict__ ab1,
    const float* __restrict__ aw2, const float* __restrict__ ab2,
    float* __restrict__ Wd, float* __restrict__ Aa)
{
    const int t = threadIdx.x;
    const int bs0 = blockIdx.x * 2;
    __shared__ float hy[2][ST];
    __shared__ float hdn_s[2][H1];
    __shared__ float hda_s[2][H1];
    if (t < 2 * ST)
        hy[t >> 7][t & 127] = hyper[(size_t)bs0 * ST + t];
    __syncthreads();
    if (t < 64) {
        const int q = t >> 5, c = t & 31;
        float acc = b1[c];
#pragma unroll 4
        for (int k = 0; k < ST; ++k) acc = fmaf(hy[q][k], w1[k * H1 + c], acc);
        hdn_s[q][c] = fmaxf(acc, 0.f);
    } else if (t < 128) {
        const int tt = t - 64;
        const int q = tt >> 5, c = tt & 31;
        float acc = ab1[c];
#pragma unroll 4
        for (int k = 0; k < ST; ++k) acc = fmaf(hy[q][k], aw1[k * H1 + c], acc);
        hda_s[q][c] = fmaxf(acc, 0.f);
    }
    __syncthreads();
    if (t < 256) {
        const int q = t >> 7, c = t & 127;
        float a = ab2[c];
#pragma unroll
        for (int k = 0; k < H1; ++k)
            a = fmaf(hda_s[q][k], aw2[k * 128 + c], a);
        Aa[(size_t)(bs0 + q) * 128 + c] = fabsf(a);
    }
#pragma unroll
    for (int p = 0; p < 2; ++p) {
        const int e = t * 4 + p * 2048;
        const float4 bb = *(const float4*)&b2[e];
        float4 a0 = bb, a1 = bb;
#pragma unroll
        for (int kq = 0; kq < 8; ++kq) {
            const float4 h0 = *(const float4*)&hdn_s[0][kq * 4];
            const float4 h1 = *(const float4*)&hdn_s[1][kq * 4];
#pragma unroll
            for (int c = 0; c < 4; ++c) {
                const float4 wv = *(const float4*)&w2[(size_t)(kq * 4 + c) * 4096 + e];
                const float s0 = (c == 0) ? h0.x : (c == 1) ? h0.y : (c == 2) ? h0.z : h0.w;
                const float s1 = (c == 0) ? h1.x : (c == 1) ? h1.y : (c == 2) ? h1.z : h1.w;
                a0.x = fmaf(s0, wv.x, a0.x); a0.y = fmaf(s0, wv.y, a0.y);
                a0.z = fmaf(s0, wv.z, a0.z); a0.w = fmaf(s0, wv.w, a0.w);
                a1.x = fmaf(s1, wv.x, a1.x); a1.y = fmaf(s1, wv.y, a1.y);
                a1.z = fmaf(s1, wv.z, a1.z); a1.w = fmaf(s1, wv.w, a1.w);
            }
        }
        a0.x = fabsf(a0.x); a0.y = fabsf(a0.y); a0.z = fabsf(a0.z); a0.w = fabsf(a0.w);
        a1.x = fabsf(a1.x); a1.y = fabsf(a1.y); a1.z = fabsf(a1.z); a1.w = fabsf(a1.w);
        *(float4*)&Wd[(size_t)(bs0 + 0) * 4096 + e] = a0;
        *(float4*)&Wd[(size_t)(bs0 + 1) * 4096 + e] = a1;
    }
}

// ------- Kernel 2: per (b,s): h = x@W via bf16 MFMA; exact-f32 e1/e2 ---------
// e1 = x.(W@a1): wa vectors computed once in f32 -> no bf16 error on the exp path.
// Writes HbT[bs][o][n] bf16 and E1/E2 pre-scaled by log2(e).
__global__ __launch_bounds__(256) void k_h(
    const float* __restrict__ x, const float* __restrict__ Wd,
    const float* __restrict__ Aa,
    ushort_t* __restrict__ HbT, float* __restrict__ E1, float* __restrict__ E2)
{
    const int bs = blockIdx.x;
    const int tid = threadIdx.x;
    const int wid = tid >> 6;
    const int lane = tid & 63;
    const int l15 = lane & 15;
    const int lhi = lane >> 4;

    __shared__ ushort_t Wt[IF * OF];   // 8 KB  W^T [o][k] bf16, XOR-swizzled
    __shared__ float wa1s[IF], wa2s[IF];
    __shared__ float a1s[OF], a2s[OF];

    if (tid < 64) a1s[tid] = Aa[(size_t)bs * 128 + tid];
    else if (tid < 128) a2s[tid - 64] = Aa[(size_t)bs * 128 + tid];

    // transpose W (f32 [k][o]) -> bf16 Wt[o][k ^ ((o&7)<<3)]
    {
        const float4* w4 = (const float4*)(Wd + (size_t)bs * 4096);
#pragma unroll
        for (int p = 0; p < 4; ++p) {
            const int idx = tid + p * 256;          // float4 units, 1024 total
            const float4 f = w4[idx];
            const int k = (idx * 4) >> 6;
            const int o0 = (idx * 4) & 63;
            Wt[(o0 + 0) * 64 + (k ^ (((o0 + 0) & 7) << 3))] = f2bf(f.x);
            Wt[(o0 + 1) * 64 + (k ^ (((o0 + 1) & 7) << 3))] = f2bf(f.y);
            Wt[(o0 + 2) * 64 + (k ^ (((o0 + 2) & 7) << 3))] = f2bf(f.z);
            Wt[(o0 + 3) * 64 + (k ^ (((o0 + 3) & 7) << 3))] = f2bf(f.w);
        }
    }
    __syncthreads();

    // wa1/wa2 = W @ a1, W @ a2 (exact f32; threads 0..63, one k-row each)
    if (tid < 64) {
        const float4* wr = (const float4*)(Wd + (size_t)bs * 4096 + tid * 64);
        float s1 = 0.f, s2 = 0.f;
#pragma unroll
        for (int q = 0; q < 16; ++q) {
            const float4 f = wr[q];
            const float4 u = *(const float4*)&a1s[q * 4];
            const float4 v = *(const float4*)&a2s[q * 4];
            s1 += f.x * u.x + f.y * u.y + f.z * u.z + f.w * u.w;
            s2 += f.x * v.x + f.y * v.y + f.z * v.z + f.w * v.w;
        }
        wa1s[tid] = s1; wa2s[tid] = s2;
    }
    __syncthreads();

    // e1/e2: exact f32 row dot (row = tid), pre-scaled by log2e
    {
        const float4* xr = (const float4*)(x + ((size_t)bs * NN + tid) * IF);
        float s1 = 0.f, s2 = 0.f;
#pragma unroll
        for (int q = 0; q < 16; ++q) {
            const float4 f = xr[q];
            const float4 u = *(const float4*)&wa1s[q * 4];
            const float4 v = *(const float4*)&wa2s[q * 4];
            s1 += f.x * u.x + f.y * u.y + f.z * u.z + f.w * u.w;
            s2 += f.x * v.x + f.y * v.y + f.z * v.z + f.w * v.w;
        }
        E1[(size_t)bs * NN + tid] = s1 * LOG2E;
        E2[(size_t)bs * NN + tid] = s2 * LOG2E;
    }

    // ---- MFMA: h = x(256x64) @ W(64x64); wave owns rows wid*64..+63
    f32x4 acc[4][4];
#pragma unroll
    for (int mt = 0; mt < 4; ++mt)
#pragma unroll
        for (int nt = 0; nt < 4; ++nt) acc[mt][nt] = (f32x4){0.f, 0.f, 0.f, 0.f};

    short8 af[4][2];
#pragma unroll
    for (int mt = 0; mt < 4; ++mt) {
        const int row = wid * 64 + mt * 16 + l15;
        const float* xrow = x + ((size_t)bs * NN + row) * IF;
#pragma unroll
        for (int ks = 0; ks < 2; ++ks) {
            const int k0 = ks * 32 + lhi * 8;
            const float4 fa = *(const float4*)&xrow[k0];
            const float4 fb = *(const float4*)&xrow[k0 + 4];
            short8 pk;
            pk[0] = (short)f2bf(fa.x); pk[1] = (short)f2bf(fa.y);
            pk[2] = (short)f2bf(fa.z); pk[3] = (short)f2bf(fa.w);
            pk[4] = (short)f2bf(fb.x); pk[5] = (short)f2bf(fb.y);
            pk[6] = (short)f2bf(fb.z); pk[7] = (short)f2bf(fb.w);
            af[mt][ks] = pk;
        }
    }
    short8 bfr[4][2];
#pragma unroll
    for (int nt = 0; nt < 4; ++nt) {
        const int o = nt * 16 + l15;
#pragma unroll
        for (int ks = 0; ks < 2; ++ks) {
            const int k0 = ks * 32 + lhi * 8;
            bfr[nt][ks] = *(const short8*)&Wt[o * 64 + (k0 ^ ((o & 7) << 3))];
        }
    }
#pragma unroll
    for (int mt = 0; mt < 4; ++mt)
#pragma unroll
        for (int nt = 0; nt < 4; ++nt) {
            acc[mt][nt] = __builtin_amdgcn_mfma_f32_16x16x32_bf16(
                af[mt][0], bfr[nt][0], acc[mt][nt], 0, 0, 0);
            acc[mt][nt] = __builtin_amdgcn_mfma_f32_16x16x32_bf16(
                af[mt][1], bfr[nt][1], acc[mt][nt], 0, 0, 0);
        }

    // epilogue: HbT[o][n], 4 consecutive rows per (mt,nt) -> 8B store
    ushort_t* hb = HbT + (size_t)bs * (OF * NN);
#pragma unroll
    for (int mt = 0; mt < 4; ++mt) {
        const int rbase = wid * 64 + mt * 16 + lhi * 4;
#pragma unroll
        for (int nt = 0; nt < 4; ++nt) {
            const int o = nt * 16 + l15;
            short4_t pk;
            pk[0] = (short)f2bf(acc[mt][nt][0]);
            pk[1] = (short)f2bf(acc[mt][nt][1]);
            pk[2] = (short)f2bf(acc[mt][nt][2]);
            pk[3] = (short)f2bf(acc[mt][nt][3]);
            *(short4_t*)(hb + (size_t)o * NN + rbase) = pk;
        }
    }
}

// ------ Kernel 3a: softmax-over-s stats, PACKED bf16 (M',R) -> MR[b][i][j] ---
// All values in the log2-scaled domain; leaky == fmax(v, 0.2v).
__global__ __launch_bounds__(256) void k_softstats(
    const float* __restrict__ E1, const float* __restrict__ E2,
    const int* __restrict__ Adj, unsigned int* __restrict__ MR)
{
    const int bid = blockIdx.x;        // b*64 + ig
    const int b = bid >> 6, i0 = (bid & 63) * 4;
    const int t = threadIdx.x;         // j
    __shared__ float e1s[4][SS];
    {
        const int ii = t >> 6, s = t & 63;
        e1s[ii][s] = E1[(size_t)(b * SS + s) * NN + i0 + ii];
    }
    float e2r[SS];
#pragma unroll
    for (int s = 0; s < SS; ++s)
        e2r[s] = E2[(size_t)(b * SS + s) * NN + t];
    __syncthreads();

#pragma unroll
    for (int ii = 0; ii < 4; ++ii) {
        float v[SS];
        float mx = -3.0e38f;
#pragma unroll
        for (int s = 0; s < SS; ++s) {
            float u = e1s[ii][s] + e2r[s];
            u = fmaxf(u, ALPHA * u);
            v[s] = u;
            mx = fmaxf(mx, u);
        }
        const unsigned int mu = (unsigned int)f2bf(mx);
        const float mUse = __uint_as_float(mu << 16);
        float sum = 0.f;
#pragma unroll
        for (int s = 0; s < SS; ++s)
            sum += exp2f(v[s] - mUse);
        const int adj = Adj[(size_t)(i0 + ii) * NN + t];
        const float r = (adj > 0) ? (1.f / sum) : -0.015625f;
        MR[(size_t)(b * NN + i0 + ii) * NN + t] =
            (mu << 16) | (unsigned int)f2bf(r);
    }
}

// ------ Kernel 3b: per (b,s): O = ELU(A(256x256) @ H(256x64)) via bf16 MFMA --
// 8 waves/block; MR loads for BOTH mt hoisted to chunk top (16 loads in flight).
__global__ __launch_bounds__(512) void k_attn(
    const ushort_t* __restrict__ HbT, const float* __restrict__ E1,
    const float* __restrict__ E2, const unsigned int* __restrict__ MR,
    float* __restrict__ out)
{
    const int bs = blockIdx.x;        // b*64 + s
    const int b = bs >> 6;
    const int tid = threadIdx.x;
    const int wid = tid >> 6;         // wave 0..7 -> output rows wid*32..+31
    const int lane = tid & 63;
    const int l15 = lane & 15;
    const int lhi = lane >> 4;

    __shared__ float e2s[NN];
    if (tid < NN) e2s[tid] = E2[(size_t)bs * NN + tid];
    __syncthreads();

    float e1r[2];
#pragma unroll
    for (int mt = 0; mt < 2; ++mt)
        e1r[mt] = E1[(size_t)bs * NN + wid * 32 + mt * 16 + l15];

    f32x4 acc[2][4];
#pragma unroll
    for (int mt = 0; mt < 2; ++mt)
#pragma unroll
        for (int nt = 0; nt < 4; ++nt) acc[mt][nt] = (f32x4){0.f, 0.f, 0.f, 0.f};

    const ushort_t* hb = HbT + (size_t)bs * (OF * NN);
    const unsigned int* mrb = MR + ((size_t)b * NN) * NN;
    const uint4* mrow0 = (const uint4*)(mrb + (size_t)(wid * 32 + l15) * NN);
    const uint4* mrow1 = (const uint4*)(mrb + (size_t)(wid * 32 + 16 + l15) * NN);

    for (int ch = 0; ch < 4; ++ch) {
        // ---- B fragments (8 x 16B, independent)
        short8 bfr[4][2];
#pragma unroll
        for (int nt = 0; nt < 4; ++nt) {
            const int o = nt * 16 + l15;
#pragma unroll
            for (int ks = 0; ks < 2; ++ks) {
                const int j0 = ch * 64 + ks * 32 + lhi * 8;
                bfr[nt][ks] = *(const short8*)(hb + (size_t)o * NN + j0);
            }
        }
        // ---- MR loads for BOTH mt hoisted (8 x dwordx4 in flight)
        uint4 mq[2][2][2];
#pragma unroll
        for (int ks = 0; ks < 2; ++ks) {
            const int qi = (ch * 64 + ks * 32 + lhi * 8) >> 2;
            mq[0][ks][0] = mrow0[qi]; mq[0][ks][1] = mrow0[qi + 1];
            mq[1][ks][0] = mrow1[qi]; mq[1][ks][1] = mrow1[qi + 1];
        }
        // ---- e2 slices
        float e2v[2][8];
#pragma unroll
        for (int ks = 0; ks < 2; ++ks) {
            const int k0 = ch * 64 + ks * 32 + lhi * 8;
            const float4 lo = *(const float4*)&e2s[k0];
            const float4 hi = *(const float4*)&e2s[k0 + 4];
            e2v[ks][0] = lo.x; e2v[ks][1] = lo.y; e2v[ks][2] = lo.z; e2v[ks][3] = lo.w;
            e2v[ks][4] = hi.x; e2v[ks][5] = hi.y; e2v[ks][6] = hi.z; e2v[ks][7] = hi.w;
        }
        // ---- A fragments + MFMA
#pragma unroll
        for (int mt = 0; mt < 2; ++mt) {
            const float e1v = e1r[mt];
            short8 af[2];
#pragma unroll
            for (int ks = 0; ks < 2; ++ks) {
                const unsigned int wv[8] = {
                    mq[mt][ks][0].x, mq[mt][ks][0].y, mq[mt][ks][0].z, mq[mt][ks][0].w,
                    mq[mt][ks][1].x, mq[mt][ks][1].y, mq[mt][ks][1].z, mq[mt][ks][1].w};
                short8 pk;
#pragma unroll
                for (int kk = 0; kk < 8; ++kk) {
                    const float Mf = __uint_as_float(wv[kk] & 0xFFFF0000u);
                    const float Rf = __uint_as_float(wv[kk] << 16);
                    float v = e1v + e2v[ks][kk];
                    v = fmaxf(v, ALPHA * v);
                    const float a = (Rf < 0.f) ? -Rf : exp2f(v - Mf) * Rf;
                    pk[kk] = (short)f2bf(a);
                }
                af[ks] = pk;
            }
#pragma unroll
            for (int nt = 0; nt < 4; ++nt) {
                acc[mt][nt] = __builtin_amdgcn_mfma_f32_16x16x32_bf16(
                    af[0], bfr[nt][0], acc[mt][nt], 0, 0, 0);
                acc[mt][nt] = __builtin_amdgcn_mfma_f32_16x16x32_bf16(
                    af[1], bfr[nt][1], acc[mt][nt], 0, 0, 0);
            }
        }
    }

    // ---- epilogue: ELU + store f32
    float* ob = out + (size_t)bs * (NN * OF);
#pragma unroll
    for (int mt = 0; mt < 2; ++mt) {
        const int rbase = wid * 32 + mt * 16 + lhi * 4;
#pragma unroll
        for (int nt = 0; nt < 4; ++nt) {
            const int o = nt * 16 + l15;
#pragma unroll
            for (int reg = 0; reg < 4; ++reg) {
                float v = acc[mt][nt][reg];
                v = (v > 0.f) ? v : (__expf(v) - 1.f);
                ob[(size_t)(rbase + reg) * OF + o] = v;
            }
        }
    }
}

extern "C" void kernel_launch(void* const* d_in, const int* in_sizes, int n_in,
                              void* d_out, int out_size, void* d_ws, size_t ws_size,
                              hipStream_t stream)
{
    const float* hyper = (const float*)d_in[0];
    const float* x     = (const float*)d_in[1];
    const int*   Adj   = (const int*)d_in[2];
    const float* w1    = (const float*)d_in[3];
    const float* b1    = (const float*)d_in[4];
    const float* w2    = (const float*)d_in[5];
    const float* b2    = (const float*)d_in[6];
    const float* aw1   = (const float*)d_in[7];
    const float* ab1   = (const float*)d_in[8];
    const float* aw2   = (const float*)d_in[9];
    const float* ab2   = (const float*)d_in[10];
    float* out = (float*)d_out;

    float* ws      = (float*)d_ws;
    float* Wd      = ws;                      // 512*4096
    float* Aa      = Wd + 2097152;            // 512*128
    ushort_t* HbT  = (ushort_t*)(Aa + 65536); // 512*64*256 bf16
    float* E1      = (float*)(HbT + 8388608); // 512*256 (log2e-scaled)
    float* E2      = E1 + 131072;             // 512*256 (log2e-scaled)
    unsigned int* MRp = (unsigned int*)(E2 + 131072); // 8*256*256 packed

    k_hyper2<<<dim3(256), dim3(512), 0, stream>>>(hyper, w1, b1, w2, b2,
                                                  aw1, ab1, aw2, ab2, Wd, Aa);
    k_h<<<dim3(512), dim3(256), 0, stream>>>(x, Wd, Aa, HbT, E1, E2);
    k_softstats<<<dim3(512), dim3(256), 0, stream>>>(E1, E2, Adj, MRp);
    k_attn<<<dim3(512), dim3(512), 0, stream>>>(HbT, E1, E2, MRp, out);
}

// Round 10
// 75.229 us; speedup vs baseline: 4.2494x; 1.1724x over previous
//
#include <hip/hip_runtime.h>
#include <hip/hip_bf16.h>
#include <math.h>

#define BB 8
#define SS 64
#define NN 256
#define ST 128
#define IF 64
#define OF 64
#define H1 32
#define ALPHA 0.2f
#define LOG2E 1.4426950408889634f

typedef short short8 __attribute__((ext_vector_type(8)));
typedef short short4_t __attribute__((ext_vector_type(4)));
typedef float f32x4 __attribute__((ext_vector_type(4)));
typedef unsigned short ushort_t;

static __device__ __forceinline__ ushort_t f2bf(float f) {
    __hip_bfloat16 h = __float2bfloat16(f);
    return *reinterpret_cast<ushort_t*>(&h);
}

// ---- Kernel 1 (fused): stage-1 MLPs + Aa + W-gen. Block = 2 bs, 512 thr ----
__global__ __launch_bounds__(512) void k_hyper2(
    const float* __restrict__ hyper,
    const float* __restrict__ w1, const float* __restrict__ b1,
    const float* __restrict__ w2, const float* __restrict__ b2,
    const float* __restrict__ aw1, const float* __restrict__ ab1,
    const float* __restrict__ aw2, const float* __restrict__ ab2,
    float* __restrict__ Wd, float* __restrict__ Aa)
{
    const int t = threadIdx.x;
    const int bs0 = blockIdx.x * 2;
    __shared__ float hy[2][ST];
    __shared__ float hdn_s[2][H1];
    __shared__ float hda_s[2][H1];
    if (t < 2 * ST)
        hy[t >> 7][t & 127] = hyper[(size_t)bs0 * ST + t];
    __syncthreads();
    if (t < 64) {
        const int q = t >> 5, c = t & 31;
        float acc = b1[c];
#pragma unroll 4
        for (int k = 0; k < ST; ++k) acc = fmaf(hy[q][k], w1[k * H1 + c], acc);
        hdn_s[q][c] = fmaxf(acc, 0.f);
    } else if (t < 128) {
        const int tt = t - 64;
        const int q = tt >> 5, c = tt & 31;
        float acc = ab1[c];
#pragma unroll 4
        for (int k = 0; k < ST; ++k) acc = fmaf(hy[q][k], aw1[k * H1 + c], acc);
        hda_s[q][c] = fmaxf(acc, 0.f);
    }
    __syncthreads();
    if (t < 256) {
        const int q = t >> 7, c = t & 127;
        float a = ab2[c];
#pragma unroll
        for (int k = 0; k < H1; ++k)
            a = fmaf(hda_s[q][k], aw2[k * 128 + c], a);
        Aa[(size_t)(bs0 + q) * 128 + c] = fabsf(a);
    }
#pragma unroll
    for (int p = 0; p < 2; ++p) {
        const int e = t * 4 + p * 2048;
        const float4 bb = *(const float4*)&b2[e];
        float4 a0 = bb, a1 = bb;
#pragma unroll
        for (int kq = 0; kq < 8; ++kq) {
            const float4 h0 = *(const float4*)&hdn_s[0][kq * 4];
            const float4 h1 = *(const float4*)&hdn_s[1][kq * 4];
#pragma unroll
            for (int c = 0; c < 4; ++c) {
                const float4 wv = *(const float4*)&w2[(size_t)(kq * 4 + c) * 4096 + e];
                const float s0 = (c == 0) ? h0.x : (c == 1) ? h0.y : (c == 2) ? h0.z : h0.w;
                const float s1 = (c == 0) ? h1.x : (c == 1) ? h1.y : (c == 2) ? h1.z : h1.w;
                a0.x = fmaf(s0, wv.x, a0.x); a0.y = fmaf(s0, wv.y, a0.y);
                a0.z = fmaf(s0, wv.z, a0.z); a0.w = fmaf(s0, wv.w, a0.w);
                a1.x = fmaf(s1, wv.x, a1.x); a1.y = fmaf(s1, wv.y, a1.y);
                a1.z = fmaf(s1, wv.z, a1.z); a1.w = fmaf(s1, wv.w, a1.w);
            }
        }
        a0.x = fabsf(a0.x); a0.y = fabsf(a0.y); a0.z = fabsf(a0.z); a0.w = fabsf(a0.w);
        a1.x = fabsf(a1.x); a1.y = fabsf(a1.y); a1.z = fabsf(a1.z); a1.w = fabsf(a1.w);
        *(float4*)&Wd[(size_t)(bs0 + 0) * 4096 + e] = a0;
        *(float4*)&Wd[(size_t)(bs0 + 1) * 4096 + e] = a1;
    }
}

// ------- Kernel 2: per (b,s): h = x@W via bf16 MFMA; exact-f32 e1/e2 ---------
// Writes h in fragment-native layout HbTw[bs][o/16][n/8][o%16][n%8] (bf16)
// and E1/E2 pre-scaled by log2(e).
__global__ __launch_bounds__(256) void k_h(
    const float* __restrict__ x, const float* __restrict__ Wd,
    const float* __restrict__ Aa,
    ushort_t* __restrict__ HbTw, float* __restrict__ E1, float* __restrict__ E2)
{
    const int bs = blockIdx.x;
    const int tid = threadIdx.x;
    const int wid = tid >> 6;
    const int lane = tid & 63;
    const int l15 = lane & 15;
    const int lhi = lane >> 4;

    __shared__ ushort_t Wt[IF * OF];   // 8 KB  W^T [o][k] bf16, XOR-swizzled
    __shared__ float wa1s[IF], wa2s[IF];
    __shared__ float a1s[OF], a2s[OF];

    if (tid < 64) a1s[tid] = Aa[(size_t)bs * 128 + tid];
    else if (tid < 128) a2s[tid - 64] = Aa[(size_t)bs * 128 + tid];

    // transpose W (f32 [k][o]) -> bf16 Wt[o][k ^ ((o&7)<<3)]
    {
        const float4* w4 = (const float4*)(Wd + (size_t)bs * 4096);
#pragma unroll
        for (int p = 0; p < 4; ++p) {
            const int idx = tid + p * 256;          // float4 units, 1024 total
            const float4 f = w4[idx];
            const int k = (idx * 4) >> 6;
            const int o0 = (idx * 4) & 63;
            Wt[(o0 + 0) * 64 + (k ^ (((o0 + 0) & 7) << 3))] = f2bf(f.x);
            Wt[(o0 + 1) * 64 + (k ^ (((o0 + 1) & 7) << 3))] = f2bf(f.y);
            Wt[(o0 + 2) * 64 + (k ^ (((o0 + 2) & 7) << 3))] = f2bf(f.z);
            Wt[(o0 + 3) * 64 + (k ^ (((o0 + 3) & 7) << 3))] = f2bf(f.w);
        }
    }
    __syncthreads();

    // wa1/wa2 = W @ a1, W @ a2 (exact f32; threads 0..63, one k-row each)
    if (tid < 64) {
        const float4* wr = (const float4*)(Wd + (size_t)bs * 4096 + tid * 64);
        float s1 = 0.f, s2 = 0.f;
#pragma unroll
        for (int q = 0; q < 16; ++q) {
            const float4 f = wr[q];
            const float4 u = *(const float4*)&a1s[q * 4];
            const float4 v = *(const float4*)&a2s[q * 4];
            s1 += f.x * u.x + f.y * u.y + f.z * u.z + f.w * u.w;
            s2 += f.x * v.x + f.y * v.y + f.z * v.z + f.w * v.w;
        }
        wa1s[tid] = s1; wa2s[tid] = s2;
    }
    __syncthreads();

    // e1/e2: exact f32 row dot (row = tid), pre-scaled by log2e
    {
        const float4* xr = (const float4*)(x + ((size_t)bs * NN + tid) * IF);
        float s1 = 0.f, s2 = 0.f;
#pragma unroll
        for (int q = 0; q < 16; ++q) {
            const float4 f = xr[q];
            const float4 u = *(const float4*)&wa1s[q * 4];
            const float4 v = *(const float4*)&wa2s[q * 4];
            s1 += f.x * u.x + f.y * u.y + f.z * u.z + f.w * u.w;
            s2 += f.x * v.x + f.y * v.y + f.z * v.z + f.w * v.w;
        }
        E1[(size_t)bs * NN + tid] = s1 * LOG2E;
        E2[(size_t)bs * NN + tid] = s2 * LOG2E;
    }

    // ---- MFMA: h = x(256x64) @ W(64x64); wave owns rows wid*64..+63
    f32x4 acc[4][4];
#pragma unroll
    for (int mt = 0; mt < 4; ++mt)
#pragma unroll
        for (int nt = 0; nt < 4; ++nt) acc[mt][nt] = (f32x4){0.f, 0.f, 0.f, 0.f};

    short8 af[4][2];
#pragma unroll
    for (int mt = 0; mt < 4; ++mt) {
        const int row = wid * 64 + mt * 16 + l15;
        const float* xrow = x + ((size_t)bs * NN + row) * IF;
#pragma unroll
        for (int ks = 0; ks < 2; ++ks) {
            const int k0 = ks * 32 + lhi * 8;
            const float4 fa = *(const float4*)&xrow[k0];
            const float4 fb = *(const float4*)&xrow[k0 + 4];
            short8 pk;
            pk[0] = (short)f2bf(fa.x); pk[1] = (short)f2bf(fa.y);
            pk[2] = (short)f2bf(fa.z); pk[3] = (short)f2bf(fa.w);
            pk[4] = (short)f2bf(fb.x); pk[5] = (short)f2bf(fb.y);
            pk[6] = (short)f2bf(fb.z); pk[7] = (short)f2bf(fb.w);
            af[mt][ks] = pk;
        }
    }
    short8 bfr[4][2];
#pragma unroll
    for (int nt = 0; nt < 4; ++nt) {
        const int o = nt * 16 + l15;
#pragma unroll
        for (int ks = 0; ks < 2; ++ks) {
            const int k0 = ks * 32 + lhi * 8;
            bfr[nt][ks] = *(const short8*)&Wt[o * 64 + (k0 ^ ((o & 7) << 3))];
        }
    }
#pragma unroll
    for (int mt = 0; mt < 4; ++mt)
#pragma unroll
        for (int nt = 0; nt < 4; ++nt) {
            acc[mt][nt] = __builtin_amdgcn_mfma_f32_16x16x32_bf16(
                af[mt][0], bfr[nt][0], acc[mt][nt], 0, 0, 0);
            acc[mt][nt] = __builtin_amdgcn_mfma_f32_16x16x32_bf16(
                af[mt][1], bfr[nt][1], acc[mt][nt], 0, 0, 0);
        }

    // epilogue -> HbTw[o/16][n/8][o%16][n%8]: 8B store per (mt,nt)
    ushort_t* hbw = HbTw + (size_t)bs * (OF * NN);
#pragma unroll
    for (int mt = 0; mt < 4; ++mt) {
        const int nb = wid * 8 + mt * 2 + (lhi >> 1);   // n/8 for this lane's rows
        const int ne = (lhi & 1) * 4;                   // n%8 base
#pragma unroll
        for (int nt = 0; nt < 4; ++nt) {
            short4_t pk;
            pk[0] = (short)f2bf(acc[mt][nt][0]);
            pk[1] = (short)f2bf(acc[mt][nt][1]);
            pk[2] = (short)f2bf(acc[mt][nt][2]);
            pk[3] = (short)f2bf(acc[mt][nt][3]);
            *(short4_t*)(hbw + ((size_t)(nt * 32 + nb) * 16 + l15) * 8 + ne) = pk;
        }
    }
}

// ------ Kernel 3a: softmax-over-s stats, PACKED bf16 (M',R) ------------------
// Fragment-native layout: MRw[b][i/16][j/8][i%16][j%8] (uint32 = M'<<16 | R).
// All values in the log2-scaled domain; leaky == fmax(v, 0.2v).
__global__ __launch_bounds__(256) void k_softstats(
    const float* __restrict__ E1, const float* __restrict__ E2,
    const int* __restrict__ Adj, unsigned int* __restrict__ MRw)
{
    const int bid = blockIdx.x;        // b*64 + ig
    const int b = bid >> 6, i0 = (bid & 63) * 4;
    const int t = threadIdx.x;         // j
    __shared__ float e1s[4][SS];
    {
        const int ii = t >> 6, s = t & 63;
        e1s[ii][s] = E1[(size_t)(b * SS + s) * NN + i0 + ii];
    }
    float e2r[SS];
#pragma unroll
    for (int s = 0; s < SS; ++s)
        e2r[s] = E2[(size_t)(b * SS + s) * NN + t];
    __syncthreads();

#pragma unroll
    for (int ii = 0; ii < 4; ++ii) {
        float v[SS];
        float mx = -3.0e38f;
#pragma unroll
        for (int s = 0; s < SS; ++s) {
            float u = e1s[ii][s] + e2r[s];
            u = fmaxf(u, ALPHA * u);
            v[s] = u;
            mx = fmaxf(mx, u);
        }
        const unsigned int mu = (unsigned int)f2bf(mx);
        const float mUse = __uint_as_float(mu << 16);
        float sum = 0.f;
#pragma unroll
        for (int s = 0; s < SS; ++s)
            sum += exp2f(v[s] - mUse);
        const int i = i0 + ii;
        const int adj = Adj[(size_t)i * NN + t];
        const float r = (adj > 0) ? (1.f / sum) : -0.015625f;
        MRw[((((size_t)b * 16 + (i >> 4)) * 32 + (t >> 3)) * 16 + (i & 15)) * 8
            + (t & 7)] = (mu << 16) | (unsigned int)f2bf(r);
    }
}

// ------ Kernel 3b: per (b,s): O = ELU(A(256x256) @ H(256x64)) via bf16 MFMA --
// Fragment-native loads: each wave's MR load is contiguous 2KB, each B-frag
// load contiguous 1KB (L1-served for waves 2..8). 8 waves/block.
__global__ __launch_bounds__(512) void k_attn(
    const ushort_t* __restrict__ HbTw, const float* __restrict__ E1,
    const float* __restrict__ E2, const unsigned int* __restrict__ MRw,
    float* __restrict__ out)
{
    const int bs = blockIdx.x;        // b*64 + s
    const int b = bs >> 6;
    const int tid = threadIdx.x;
    const int wid = tid >> 6;         // wave 0..7 -> output rows wid*32..+31
    const int lane = tid & 63;
    const int l15 = lane & 15;
    const int lhi = lane >> 4;

    __shared__ float e2s[NN];
    if (tid < NN) e2s[tid] = E2[(size_t)bs * NN + tid];
    __syncthreads();

    float e1r[2];
#pragma unroll
    for (int mt = 0; mt < 2; ++mt)
        e1r[mt] = E1[(size_t)bs * NN + wid * 32 + mt * 16 + l15];

    f32x4 acc[2][4];
#pragma unroll
    for (int mt = 0; mt < 2; ++mt)
#pragma unroll
        for (int nt = 0; nt < 4; ++nt) acc[mt][nt] = (f32x4){0.f, 0.f, 0.f, 0.f};

    const ushort_t* hbw = HbTw + (size_t)bs * (OF * NN);
    // MRw row-group base per mt: ib = wid*2+mt, lane offset l15*8
    const unsigned int* mrb = MRw + (size_t)b * (NN * NN);
    const unsigned int* mr0 = mrb + ((size_t)(wid * 2 + 0) * 32) * 128 + l15 * 8;
    const unsigned int* mr1 = mrb + ((size_t)(wid * 2 + 1) * 32) * 128 + l15 * 8;

    for (int ch = 0; ch < 4; ++ch) {
        // ---- B fragments: contiguous 16B/lane, 1KB/inst
        short8 bfr[4][2];
#pragma unroll
        for (int nt = 0; nt < 4; ++nt) {
#pragma unroll
            for (int ks = 0; ks < 2; ++ks) {
                const int nb = ch * 8 + ks * 4 + lhi;
                bfr[nt][ks] = *(const short8*)(hbw
                    + ((size_t)(nt * 32 + nb) * 16 + l15) * 8);
            }
        }
        // ---- MR stats: contiguous 32B/lane, 2KB/inst-pair
        uint4 mq[2][2][2];
#pragma unroll
        for (int ks = 0; ks < 2; ++ks) {
            const int kb = ch * 8 + ks * 4 + lhi;
            mq[0][ks][0] = *(const uint4*)(mr0 + kb * 128);
            mq[0][ks][1] = *(const uint4*)(mr0 + kb * 128 + 4);
            mq[1][ks][0] = *(const uint4*)(mr1 + kb * 128);
            mq[1][ks][1] = *(const uint4*)(mr1 + kb * 128 + 4);
        }
        // ---- e2 slices (LDS b128)
        float e2v[2][8];
#pragma unroll
        for (int ks = 0; ks < 2; ++ks) {
            const int k0 = ch * 64 + ks * 32 + lhi * 8;
            const float4 lo = *(const float4*)&e2s[k0];
            const float4 hi = *(const float4*)&e2s[k0 + 4];
            e2v[ks][0] = lo.x; e2v[ks][1] = lo.y; e2v[ks][2] = lo.z; e2v[ks][3] = lo.w;
            e2v[ks][4] = hi.x; e2v[ks][5] = hi.y; e2v[ks][6] = hi.z; e2v[ks][7] = hi.w;
        }
        // ---- A fragments + MFMA
#pragma unroll
        for (int mt = 0; mt < 2; ++mt) {
            const float e1v = e1r[mt];
            short8 af[2];
#pragma unroll
            for (int ks = 0; ks < 2; ++ks) {
                const unsigned int wv[8] = {
                    mq[mt][ks][0].x, mq[mt][ks][0].y, mq[mt][ks][0].z, mq[mt][ks][0].w,
                    mq[mt][ks][1].x, mq[mt][ks][1].y, mq[mt][ks][1].z, mq[mt][ks][1].w};
                short8 pk;
#pragma unroll
                for (int kk = 0; kk < 8; ++kk) {
                    const float Mf = __uint_as_float(wv[kk] & 0xFFFF0000u);
                    const float Rf = __uint_as_float(wv[kk] << 16);
                    float v = e1v + e2v[ks][kk];
                    v = fmaxf(v, ALPHA * v);
                    const float a = (Rf < 0.f) ? -Rf : exp2f(v - Mf) * Rf;
                    pk[kk] = (short)f2bf(a);
                }
                af[ks] = pk;
            }
#pragma unroll
            for (int nt = 0; nt < 4; ++nt) {
                acc[mt][nt] = __builtin_amdgcn_mfma_f32_16x16x32_bf16(
                    af[0], bfr[nt][0], acc[mt][nt], 0, 0, 0);
                acc[mt][nt] = __builtin_amdgcn_mfma_f32_16x16x32_bf16(
                    af[1], bfr[nt][1], acc[mt][nt], 0, 0, 0);
            }
        }
    }

    // ---- epilogue: ELU + store f32
    float* ob = out + (size_t)bs * (NN * OF);
#pragma unroll
    for (int mt = 0; mt < 2; ++mt) {
        const int rbase = wid * 32 + mt * 16 + lhi * 4;
#pragma unroll
        for (int nt = 0; nt < 4; ++nt) {
            const int o = nt * 16 + l15;
#pragma unroll
            for (int reg = 0; reg < 4; ++reg) {
                float v = acc[mt][nt][reg];
                v = (v > 0.f) ? v : (__expf(v) - 1.f);
                ob[(size_t)(rbase + reg) * OF + o] = v;
            }
        }
    }
}

extern "C" void kernel_launch(void* const* d_in, const int* in_sizes, int n_in,
                              void* d_out, int out_size, void* d_ws, size_t ws_size,
                              hipStream_t stream)
{
    const float* hyper = (const float*)d_in[0];
    const float* x     = (const float*)d_in[1];
    const int*   Adj   = (const int*)d_in[2];
    const float* w1    = (const float*)d_in[3];
    const float* b1    = (const float*)d_in[4];
    const float* w2    = (const float*)d_in[5];
    const float* b2    = (const float*)d_in[6];
    const float* aw1   = (const float*)d_in[7];
    const float* ab1   = (const float*)d_in[8];
    const float* aw2   = (const float*)d_in[9];
    const float* ab2   = (const float*)d_in[10];
    float* out = (float*)d_out;

    float* ws      = (float*)d_ws;
    float* Wd      = ws;                      // 512*4096
    float* Aa      = Wd + 2097152;            // 512*128
    ushort_t* HbTw = (ushort_t*)(Aa + 65536); // 512*64*256 bf16, fragment-native
    float* E1      = (float*)(HbTw + 8388608);// 512*256 (log2e-scaled)
    float* E2      = E1 + 131072;             // 512*256 (log2e-scaled)
    unsigned int* MRw = (unsigned int*)(E2 + 131072); // 8*256*256, fragment-native

    k_hyper2<<<dim3(256), dim3(512), 0, stream>>>(hyper, w1, b1, w2, b2,
                                                  aw1, ab1, aw2, ab2, Wd, Aa);
    k_h<<<dim3(512), dim3(256), 0, stream>>>(x, Wd, Aa, HbTw, E1, E2);
    k_softstats<<<dim3(512), dim3(256), 0, stream>>>(E1, E2, Adj, MRw);
    k_attn<<<dim3(512), dim3(512), 0, stream>>>(HbTw, E1, E2, MRw, out);
}

// Round 11
// 73.441 us; speedup vs baseline: 4.3529x; 1.0243x over previous
//
#include <hip/hip_runtime.h>
#include <hip/hip_bf16.h>
#include <math.h>

#define BB 8
#define SS 64
#define NN 256
#define ST 128
#define IF 64
#define OF 64
#define H1 32
#define ALPHA 0.2f
#define LOG2E 1.4426950408889634f

typedef short short8 __attribute__((ext_vector_type(8)));
typedef short short4_t __attribute__((ext_vector_type(4)));
typedef float f32x4 __attribute__((ext_vector_type(4)));
typedef unsigned short ushort_t;

static __device__ __forceinline__ ushort_t f2bf(float f) {
    __hip_bfloat16 h = __float2bfloat16(f);
    return *reinterpret_cast<ushort_t*>(&h);
}

// ---- Kernel 1 (fused): stage-1 MLPs + Aa + W-gen. Block = 2 bs, 512 thr ----
__global__ __launch_bounds__(512) void k_hyper2(
    const float* __restrict__ hyper,
    const float* __restrict__ w1, const float* __restrict__ b1,
    const float* __restrict__ w2, const float* __restrict__ b2,
    const float* __restrict__ aw1, const float* __restrict__ ab1,
    const float* __restrict__ aw2, const float* __restrict__ ab2,
    float* __restrict__ Wd, float* __restrict__ Aa)
{
    const int t = threadIdx.x;
    const int bs0 = blockIdx.x * 2;
    __shared__ float hy[2][ST];
    __shared__ float hdn_s[2][H1];
    __shared__ float hda_s[2][H1];
    if (t < 2 * ST)
        hy[t >> 7][t & 127] = hyper[(size_t)bs0 * ST + t];
    __syncthreads();
    if (t < 64) {
        const int q = t >> 5, c = t & 31;
        float acc = b1[c];
#pragma unroll 4
        for (int k = 0; k < ST; ++k) acc = fmaf(hy[q][k], w1[k * H1 + c], acc);
        hdn_s[q][c] = fmaxf(acc, 0.f);
    } else if (t < 128) {
        const int tt = t - 64;
        const int q = tt >> 5, c = tt & 31;
        float acc = ab1[c];
#pragma unroll 4
        for (int k = 0; k < ST; ++k) acc = fmaf(hy[q][k], aw1[k * H1 + c], acc);
        hda_s[q][c] = fmaxf(acc, 0.f);
    }
    __syncthreads();
    if (t < 256) {
        const int q = t >> 7, c = t & 127;
        float a = ab2[c];
#pragma unroll
        for (int k = 0; k < H1; ++k)
            a = fmaf(hda_s[q][k], aw2[k * 128 + c], a);
        Aa[(size_t)(bs0 + q) * 128 + c] = fabsf(a);
    }
#pragma unroll
    for (int p = 0; p < 2; ++p) {
        const int e = t * 4 + p * 2048;
        const float4 bb = *(const float4*)&b2[e];
        float4 a0 = bb, a1 = bb;
#pragma unroll
        for (int kq = 0; kq < 8; ++kq) {
            const float4 h0 = *(const float4*)&hdn_s[0][kq * 4];
            const float4 h1 = *(const float4*)&hdn_s[1][kq * 4];
#pragma unroll
            for (int c = 0; c < 4; ++c) {
                const float4 wv = *(const float4*)&w2[(size_t)(kq * 4 + c) * 4096 + e];
                const float s0 = (c == 0) ? h0.x : (c == 1) ? h0.y : (c == 2) ? h0.z : h0.w;
                const float s1 = (c == 0) ? h1.x : (c == 1) ? h1.y : (c == 2) ? h1.z : h1.w;
                a0.x = fmaf(s0, wv.x, a0.x); a0.y = fmaf(s0, wv.y, a0.y);
                a0.z = fmaf(s0, wv.z, a0.z); a0.w = fmaf(s0, wv.w, a0.w);
                a1.x = fmaf(s1, wv.x, a1.x); a1.y = fmaf(s1, wv.y, a1.y);
                a1.z = fmaf(s1, wv.z, a1.z); a1.w = fmaf(s1, wv.w, a1.w);
            }
        }
        a0.x = fabsf(a0.x); a0.y = fabsf(a0.y); a0.z = fabsf(a0.z); a0.w = fabsf(a0.w);
        a1.x = fabsf(a1.x); a1.y = fabsf(a1.y); a1.z = fabsf(a1.z); a1.w = fabsf(a1.w);
        *(float4*)&Wd[(size_t)(bs0 + 0) * 4096 + e] = a0;
        *(float4*)&Wd[(size_t)(bs0 + 1) * 4096 + e] = a1;
    }
}

// ------- Kernel 2: per (b,s): h = x@W via bf16 MFMA; exact-f32 e1/e2 ---------
// x slice staged ONCE, coalesced, into XOR-swizzled f32 LDS; fragments and
// e-dots read from LDS (kills the strided global gathers).
__global__ __launch_bounds__(256) void k_h(
    const float* __restrict__ x, const float* __restrict__ Wd,
    const float* __restrict__ Aa,
    ushort_t* __restrict__ HbTw, float* __restrict__ E1, float* __restrict__ E2)
{
    const int bs = blockIdx.x;
    const int tid = threadIdx.x;
    const int wid = tid >> 6;
    const int lane = tid & 63;
    const int l15 = lane & 15;
    const int lhi = lane >> 4;

    __shared__ char xl[NN * IF * 4];   // 64 KB f32 x-slice, byte ^= (row&7)<<5
    __shared__ ushort_t Wt[IF * OF];   // 8 KB  W^T [o][k] bf16, XOR-swizzled
    __shared__ float wa1s[IF], wa2s[IF];
    __shared__ float a1s[OF], a2s[OF];

    if (tid < 64) a1s[tid] = Aa[(size_t)bs * 128 + tid];
    else if (tid < 128) a2s[tid - 64] = Aa[(size_t)bs * 128 + tid];

    // stage x (coalesced float4), swizzled
    {
        const float4* x4 = (const float4*)(x + (size_t)bs * NN * IF);
#pragma unroll
        for (int p = 0; p < 16; ++p) {
            const int idx = tid + p * 256;          // float4 units, 4096 total
            const int row = idx >> 4;
            const int byte = (row << 8) | ((((idx & 15) << 4)) ^ ((row & 7) << 5));
            *(float4*)(xl + byte) = x4[idx];
        }
    }
    // transpose W (f32 [k][o]) -> bf16 Wt[o][k ^ ((o&7)<<3)]
    {
        const float4* w4 = (const float4*)(Wd + (size_t)bs * 4096);
#pragma unroll
        for (int p = 0; p < 4; ++p) {
            const int idx = tid + p * 256;
            const float4 f = w4[idx];
            const int k = (idx * 4) >> 6;
            const int o0 = (idx * 4) & 63;
            Wt[(o0 + 0) * 64 + (k ^ (((o0 + 0) & 7) << 3))] = f2bf(f.x);
            Wt[(o0 + 1) * 64 + (k ^ (((o0 + 1) & 7) << 3))] = f2bf(f.y);
            Wt[(o0 + 2) * 64 + (k ^ (((o0 + 2) & 7) << 3))] = f2bf(f.z);
            Wt[(o0 + 3) * 64 + (k ^ (((o0 + 3) & 7) << 3))] = f2bf(f.w);
        }
    }
    __syncthreads();

    // wa1/wa2 = W @ a1, W @ a2 (exact f32; threads 0..63, one k-row each)
    if (tid < 64) {
        const float4* wr = (const float4*)(Wd + (size_t)bs * 4096 + tid * 64);
        float s1 = 0.f, s2 = 0.f;
#pragma unroll
        for (int q = 0; q < 16; ++q) {
            const float4 f = wr[q];
            const float4 u = *(const float4*)&a1s[q * 4];
            const float4 v = *(const float4*)&a2s[q * 4];
            s1 += f.x * u.x + f.y * u.y + f.z * u.z + f.w * u.w;
            s2 += f.x * v.x + f.y * v.y + f.z * v.z + f.w * v.w;
        }
        wa1s[tid] = s1; wa2s[tid] = s2;
    }
    __syncthreads();

    // e1/e2: exact f32 row dot from LDS (row = tid), pre-scaled by log2e
    {
        float s1 = 0.f, s2 = 0.f;
        const int rbase = tid << 8;
        const int sw = (tid & 7) << 5;
#pragma unroll
        for (int q = 0; q < 16; ++q) {
            const float4 f = *(const float4*)(xl + (rbase | ((q << 4) ^ sw)));
            const float4 u = *(const float4*)&wa1s[q * 4];
            const float4 v = *(const float4*)&wa2s[q * 4];
            s1 += f.x * u.x + f.y * u.y + f.z * u.z + f.w * u.w;
            s2 += f.x * v.x + f.y * v.y + f.z * v.z + f.w * v.w;
        }
        E1[(size_t)bs * NN + tid] = s1 * LOG2E;
        E2[(size_t)bs * NN + tid] = s2 * LOG2E;
    }

    // ---- MFMA: h = x(256x64) @ W(64x64); wave owns rows wid*64..+63
    f32x4 acc[4][4];
#pragma unroll
    for (int mt = 0; mt < 4; ++mt)
#pragma unroll
        for (int nt = 0; nt < 4; ++nt) acc[mt][nt] = (f32x4){0.f, 0.f, 0.f, 0.f};

    short8 af[4][2];
#pragma unroll
    for (int mt = 0; mt < 4; ++mt) {
        const int row = wid * 64 + mt * 16 + l15;
        const int rb = row << 8;
        const int sw = (row & 7) << 5;
#pragma unroll
        for (int ks = 0; ks < 2; ++ks) {
            const int kb = (ks * 32 + lhi * 8) * 4;   // byte offset of k0 (32B-aligned)
            const float4 fa = *(const float4*)(xl + (rb | (kb ^ sw)));
            const float4 fb = *(const float4*)(xl + (rb | ((kb + 16) ^ sw)));
            short8 pk;
            pk[0] = (short)f2bf(fa.x); pk[1] = (short)f2bf(fa.y);
            pk[2] = (short)f2bf(fa.z); pk[3] = (short)f2bf(fa.w);
            pk[4] = (short)f2bf(fb.x); pk[5] = (short)f2bf(fb.y);
            pk[6] = (short)f2bf(fb.z); pk[7] = (short)f2bf(fb.w);
            af[mt][ks] = pk;
        }
    }
    short8 bfr[4][2];
#pragma unroll
    for (int nt = 0; nt < 4; ++nt) {
        const int o = nt * 16 + l15;
#pragma unroll
        for (int ks = 0; ks < 2; ++ks) {
            const int k0 = ks * 32 + lhi * 8;
            bfr[nt][ks] = *(const short8*)&Wt[o * 64 + (k0 ^ ((o & 7) << 3))];
        }
    }
#pragma unroll
    for (int mt = 0; mt < 4; ++mt)
#pragma unroll
        for (int nt = 0; nt < 4; ++nt) {
            acc[mt][nt] = __builtin_amdgcn_mfma_f32_16x16x32_bf16(
                af[mt][0], bfr[nt][0], acc[mt][nt], 0, 0, 0);
            acc[mt][nt] = __builtin_amdgcn_mfma_f32_16x16x32_bf16(
                af[mt][1], bfr[nt][1], acc[mt][nt], 0, 0, 0);
        }

    // epilogue -> HbTw[o/16][n/8][o%16][n%8]: 8B store per (mt,nt)
    ushort_t* hbw = HbTw + (size_t)bs * (OF * NN);
#pragma unroll
    for (int mt = 0; mt < 4; ++mt) {
        const int nb = wid * 8 + mt * 2 + (lhi >> 1);
        const int ne = (lhi & 1) * 4;
#pragma unroll
        for (int nt = 0; nt < 4; ++nt) {
            short4_t pk;
            pk[0] = (short)f2bf(acc[mt][nt][0]);
            pk[1] = (short)f2bf(acc[mt][nt][1]);
            pk[2] = (short)f2bf(acc[mt][nt][2]);
            pk[3] = (short)f2bf(acc[mt][nt][3]);
            *(short4_t*)(hbw + ((size_t)(nt * 32 + nb) * 16 + l15) * 8 + ne) = pk;
        }
    }
}

// ------ Kernel 3a: softmax-over-s stats, PACKED bf16 (M',R) ------------------
// Fragment-native MRw[b][i/16][j/8][i%16][j%8]. XCD-pinned: b = blockIdx%8,
// so batch b's MR is produced on XCD b (and consumed there by k_attn).
__global__ __launch_bounds__(256) void k_softstats(
    const float* __restrict__ E1, const float* __restrict__ E2,
    const int* __restrict__ Adj, unsigned int* __restrict__ MRw)
{
    const int b = blockIdx.x & 7;
    const int i0 = (blockIdx.x >> 3) * 4;
    const int t = threadIdx.x;         // j
    __shared__ float e1s[4][SS];
    {
        const int ii = t >> 6, s = t & 63;
        e1s[ii][s] = E1[(size_t)(b * SS + s) * NN + i0 + ii];
    }
    float e2r[SS];
#pragma unroll
    for (int s = 0; s < SS; ++s)
        e2r[s] = E2[(size_t)(b * SS + s) * NN + t];
    __syncthreads();

#pragma unroll
    for (int ii = 0; ii < 4; ++ii) {
        float v[SS];
        float mx = -3.0e38f;
#pragma unroll
        for (int s = 0; s < SS; ++s) {
            float u = e1s[ii][s] + e2r[s];
            u = fmaxf(u, ALPHA * u);
            v[s] = u;
            mx = fmaxf(mx, u);
        }
        const unsigned int mu = (unsigned int)f2bf(mx);
        const float mUse = __uint_as_float(mu << 16);
        float sum = 0.f;
#pragma unroll
        for (int s = 0; s < SS; ++s)
            sum += exp2f(v[s] - mUse);
        const int i = i0 + ii;
        const int adj = Adj[(size_t)i * NN + t];
        const float r = (adj > 0) ? (1.f / sum) : -0.015625f;
        MRw[((((size_t)b * 16 + (i >> 4)) * 32 + (t >> 3)) * 16 + (i & 15)) * 8
            + (t & 7)] = (mu << 16) | (unsigned int)f2bf(r);
    }
}

// ------ Kernel 3b: O = ELU(A @ H) via bf16 MFMA. 256 thr, 1024 blocks --------
// Block = (b XCD-pinned, s, row-half). 4 waves x 32 rows. ks-split chunk loop
// keeps VGPR <= 128 (launch_bounds min-waves 4 => 4 blocks/CU).
__global__ __launch_bounds__(256, 4) void k_attn(
    const ushort_t* __restrict__ HbTw, const float* __restrict__ E1,
    const float* __restrict__ E2, const unsigned int* __restrict__ MRw,
    float* __restrict__ out)
{
    const int b = blockIdx.x & 7;            // XCD-pinned batch
    const int k2 = blockIdx.x >> 3;          // 0..127
    const int s = k2 >> 1;
    const int half = k2 & 1;
    const int bs = b * 64 + s;
    const int tid = threadIdx.x;
    const int wid = tid >> 6;                // wave 0..3
    const int lane = tid & 63;
    const int l15 = lane & 15;
    const int lhi = lane >> 4;
    const int rb0 = half * 128 + wid * 32;   // this wave's first output row

    __shared__ float e2s[NN];
    e2s[tid] = E2[(size_t)bs * NN + tid];
    __syncthreads();

    float e1r[2];
#pragma unroll
    for (int mt = 0; mt < 2; ++mt)
        e1r[mt] = E1[(size_t)bs * NN + rb0 + mt * 16 + l15];

    f32x4 acc[2][4];
#pragma unroll
    for (int mt = 0; mt < 2; ++mt)
#pragma unroll
        for (int nt = 0; nt < 4; ++nt) acc[mt][nt] = (f32x4){0.f, 0.f, 0.f, 0.f};

    const ushort_t* hbw = HbTw + (size_t)bs * (OF * NN);
    const unsigned int* mrb = MRw + (size_t)b * (NN * NN);
    const unsigned int* mr0 = mrb + ((size_t)((rb0 >> 4) + 0) * 32) * 128 + l15 * 8;
    const unsigned int* mr1 = mrb + ((size_t)((rb0 >> 4) + 1) * 32) * 128 + l15 * 8;

    for (int ch = 0; ch < 4; ++ch) {
#pragma unroll
        for (int ks = 0; ks < 2; ++ks) {
            const int kb = ch * 8 + ks * 4 + lhi;   // j/8 block index
            // B fragments: contiguous 16B/lane
            short8 bfr[4];
#pragma unroll
            for (int nt = 0; nt < 4; ++nt)
                bfr[nt] = *(const short8*)(hbw + ((size_t)(nt * 32 + kb) * 16 + l15) * 8);
            // MR stats: contiguous 32B/lane per mt
            uint4 mq[2][2];
            mq[0][0] = *(const uint4*)(mr0 + kb * 128);
            mq[0][1] = *(const uint4*)(mr0 + kb * 128 + 4);
            mq[1][0] = *(const uint4*)(mr1 + kb * 128);
            mq[1][1] = *(const uint4*)(mr1 + kb * 128 + 4);
            // e2 slice
            const int k0 = ch * 64 + ks * 32 + lhi * 8;
            const float4 lo = *(const float4*)&e2s[k0];
            const float4 hi = *(const float4*)&e2s[k0 + 4];
            const float e2v[8] = {lo.x, lo.y, lo.z, lo.w, hi.x, hi.y, hi.z, hi.w};
            // A fragments + MFMA
#pragma unroll
            for (int mt = 0; mt < 2; ++mt) {
                const float e1v = e1r[mt];
                const unsigned int wv[8] = {
                    mq[mt][0].x, mq[mt][0].y, mq[mt][0].z, mq[mt][0].w,
                    mq[mt][1].x, mq[mt][1].y, mq[mt][1].z, mq[mt][1].w};
                short8 pk;
#pragma unroll
                for (int kk = 0; kk < 8; ++kk) {
                    const float Mf = __uint_as_float(wv[kk] & 0xFFFF0000u);
                    const float Rf = __uint_as_float(wv[kk] << 16);
                    float v = e1v + e2v[kk];
                    v = fmaxf(v, ALPHA * v);
                    const float a = (Rf < 0.f) ? -Rf : exp2f(v - Mf) * Rf;
                    pk[kk] = (short)f2bf(a);
                }
#pragma unroll
                for (int nt = 0; nt < 4; ++nt)
                    acc[mt][nt] = __builtin_amdgcn_mfma_f32_16x16x32_bf16(
                        pk, bfr[nt], acc[mt][nt], 0, 0, 0);
            }
        }
    }

    // ---- epilogue: ELU + store f32
    float* ob = out + (size_t)bs * (NN * OF);
#pragma unroll
    for (int mt = 0; mt < 2; ++mt) {
        const int rbase = rb0 + mt * 16 + lhi * 4;
#pragma unroll
        for (int nt = 0; nt < 4; ++nt) {
            const int o = nt * 16 + l15;
#pragma unroll
            for (int reg = 0; reg < 4; ++reg) {
                float v = acc[mt][nt][reg];
                v = (v > 0.f) ? v : (__expf(v) - 1.f);
                ob[(size_t)(rbase + reg) * OF + o] = v;
            }
        }
    }
}

extern "C" void kernel_launch(void* const* d_in, const int* in_sizes, int n_in,
                              void* d_out, int out_size, void* d_ws, size_t ws_size,
                              hipStream_t stream)
{
    const float* hyper = (const float*)d_in[0];
    const float* x     = (const float*)d_in[1];
    const int*   Adj   = (const int*)d_in[2];
    const float* w1    = (const float*)d_in[3];
    const float* b1    = (const float*)d_in[4];
    const float* w2    = (const float*)d_in[5];
    const float* b2    = (const float*)d_in[6];
    const float* aw1   = (const float*)d_in[7];
    const float* ab1   = (const float*)d_in[8];
    const float* aw2   = (const float*)d_in[9];
    const float* ab2   = (const float*)d_in[10];
    float* out = (float*)d_out;

    float* ws      = (float*)d_ws;
    float* Wd      = ws;                      // 512*4096
    float* Aa      = Wd + 2097152;            // 512*128
    ushort_t* HbTw = (ushort_t*)(Aa + 65536); // 512*64*256 bf16, fragment-native
    float* E1      = (float*)(HbTw + 8388608);// 512*256 (log2e-scaled)
    float* E2      = E1 + 131072;             // 512*256 (log2e-scaled)
    unsigned int* MRw = (unsigned int*)(E2 + 131072); // 8*256*256, fragment-native

    k_hyper2<<<dim3(256), dim3(512), 0, stream>>>(hyper, w1, b1, w2, b2,
                                                  aw1, ab1, aw2, ab2, Wd, Aa);
    k_h<<<dim3(512), dim3(256), 0, stream>>>(x, Wd, Aa, HbTw, E1, E2);
    k_softstats<<<dim3(512), dim3(256), 0, stream>>>(E1, E2, Adj, MRw);
    k_attn<<<dim3(1024), dim3(256), 0, stream>>>(HbTw, E1, E2, MRw, out);
}